// Round 2
// baseline (10001.623 us; speedup 1.0000x reference)
//
#include <hip/hip_runtime.h>
#include <hip/hip_bf16.h>

// ============================================================================
// HybridViT forward: CNN stem (3x conv7x7s2+ReLU+maxpool7x7s1p1) -> flatten
// -> linear -> +cls/pos -> 6x transformer layers -> head LN -> classifier.
// Round 2: same math as round 1 but CNN stem processed in 4 chunks of 64
// patches to cap workspace at ~97 MB (round 1's ~346 MB likely overflowed
// d_ws -> GPU memory fault -> abort).
// ============================================================================

typedef __hip_bfloat16 bf16;

#define CHUNK 64   // patches per CNN chunk (256 total / 4 chunks)

// ---------- K1: patchify + conv1(1->32,7x7,s2) + ReLU + pool -> pool1 bf16 [CHUNK,32,103,103]
__global__ __launch_bounds__(256) void k1_conv1_pool(
    const float* __restrict__ img, const float* __restrict__ w,
    bf16* __restrict__ pool1, int n_base)
{
  __shared__ __align__(16) float in_s[33*224];     // input rows (fp32), padded width
  __shared__ __align__(16) float conv_s[4*14*112]; // conv+relu tile for 4 oc
  __shared__ __align__(16) float w_s[32*56];       // weights, ky rows padded to 8
  const int strip = blockIdx.x;        // 0..12, 8 pooled rows each
  const int n = blockIdx.y;            // local patch 0..CHUNK-1
  const int ng = n_base + n;           // global patch 0..255
  const int p0 = strip*8;
  const int PR = min(8, 103-p0);
  const int cr0 = max(p0-1, 0);
  const int cr1 = min(p0+PR+4, 106);
  const int CR = cr1-cr0+1;            // <=14 conv rows
  const int ir0 = 2*cr0;
  const int IR = 2*CR+5;               // <=33 input rows
  const int b = ng>>4, gh = (ng>>2)&3, gw = ng&3;
  const float* ibase = img + b*774400 + (gh*220)*880 + gw*220;

  for (int idx = threadIdx.x; idx < IR*224; idx += 256){
    int r = idx/224, c = idx - r*224;
    in_s[idx] = (c < 220) ? ibase[(ir0+r)*880 + c] : 0.f;
  }
  for (int idx = threadIdx.x; idx < 32*56; idx += 256){
    int oc = idx/56, k = idx - oc*56; int ky = k>>3, kx = k&7;
    w_s[idx] = (kx < 7 && ky < 7) ? w[oc*49 + ky*7 + kx] : 0.f;
  }
  __syncthreads();

  for (int grp = 0; grp < 8; grp++){   // 8 groups of 4 output channels
    for (int t = threadIdx.x; t < CR*27; t += 256){
      int r = t/27, g = t - r*27; int c0 = g*4;   // 4-col tile
      float acc[4][4] = {};
      for (int ky = 0; ky < 7; ky++){
        const float* ip = &in_s[(2*r+ky)*224 + 2*c0];
        float iv[13];
        #pragma unroll
        for (int i = 0; i < 13; i++) iv[i] = ip[i];
        #pragma unroll
        for (int oc = 0; oc < 4; oc++){
          const float* wp = &w_s[(grp*4+oc)*56 + ky*8];
          float4 wa = *(const float4*)wp;
          float4 wb = *(const float4*)(wp+4);
          float wk[7] = {wa.x,wa.y,wa.z,wa.w,wb.x,wb.y,wb.z};
          #pragma unroll
          for (int kx = 0; kx < 7; kx++)
            #pragma unroll
            for (int j = 0; j < 4; j++)
              acc[oc][j] += iv[2*j+kx]*wk[kx];
        }
      }
      #pragma unroll
      for (int oc = 0; oc < 4; oc++)
        #pragma unroll
        for (int j = 0; j < 4; j++)
          conv_s[(oc*14 + r)*112 + c0 + j] = fmaxf(acc[oc][j], 0.f);
    }
    __syncthreads();
    for (int t = threadIdx.x; t < PR*103; t += 256){
      int pr = t/103, pc = t - pr*103;
      int py = p0 + pr;
      float m0v=-1e30f, m1v=-1e30f, m2v=-1e30f, m3v=-1e30f;
      for (int dy = 0; dy < 7; dy++){
        int rr = py-1+dy;
        if (rr < 0 || rr > 106) continue;
        int lr = rr - cr0;
        for (int dx = 0; dx < 7; dx++){
          int cc = pc-1+dx;
          if (cc < 0 || cc > 106) continue;
          m0v = fmaxf(m0v, conv_s[(0*14+lr)*112 + cc]);
          m1v = fmaxf(m1v, conv_s[(1*14+lr)*112 + cc]);
          m2v = fmaxf(m2v, conv_s[(2*14+lr)*112 + cc]);
          m3v = fmaxf(m3v, conv_s[(3*14+lr)*112 + cc]);
        }
      }
      int obase = ((n*32 + grp*4)*103 + py)*103 + pc;
      pool1[obase]           = __float2bfloat16(m0v);
      pool1[obase + 10609]   = __float2bfloat16(m1v);
      pool1[obase + 2*10609] = __float2bfloat16(m2v);
      pool1[obase + 3*10609] = __float2bfloat16(m3v);
    }
    __syncthreads();
  }
}

// ---------- K2: conv2(32->64,7x7,s2) + ReLU -> conv2out bf16 [CHUNK,64,49,49]
__global__ __launch_bounds__(256) void k2_conv2(
    const bf16* __restrict__ pool1, const float* __restrict__ w,
    bf16* __restrict__ conv2out)
{
  __shared__ __align__(16) float in_s[2*43*112];
  __shared__ __align__(16) float w_s[2*16*56];
  const int ocg = blockIdx.x & 3, rs = blockIdx.x >> 2;   // grid.x=12 (4 ocg x 3 strips)
  const int n = blockIdx.y;                                // local patch
  const int r0 = rs*19;
  const int ocbase = ocg*16;
  const int g = threadIdx.x % 13, r = threadIdx.x / 13;   // 13 col-groups x 19 rows
  const int c0 = g*4;
  const bool act = (r < 19) && (r0 + r < 49);
  const int ir0 = 2*r0;
  float acc[16][4] = {};
  for (int ic0 = 0; ic0 < 32; ic0 += 2){
    __syncthreads();
    for (int idx = threadIdx.x; idx < 2*43*112; idx += 256){
      int ic = idx/(43*112); int rem = idx - ic*(43*112);
      int rr = rem/112, c = rem - rr*112;
      int grow = ir0 + rr;
      in_s[idx] = (c < 103 && grow < 103) ?
        __bfloat162float(pool1[((n*32 + ic0+ic)*103 + grow)*103 + c]) : 0.f;
    }
    for (int idx = threadIdx.x; idx < 2*16*56; idx += 256){
      int ic = idx/(16*56); int rem = idx - ic*(16*56);
      int oc = rem/56; int k = rem - oc*56; int ky = k>>3, kx = k&7;
      w_s[idx] = (kx < 7) ? w[((ocbase+oc)*32 + ic0+ic)*49 + ky*7 + kx] : 0.f;
    }
    __syncthreads();
    if (act){
      for (int ic = 0; ic < 2; ic++){
        for (int ky = 0; ky < 7; ky++){
          const float* ip = &in_s[ic*43*112 + (2*r+ky)*112 + 2*c0];
          float iv[13];
          #pragma unroll
          for (int i = 0; i < 13; i++) iv[i] = ip[i];
          #pragma unroll
          for (int oc = 0; oc < 16; oc++){
            const float* wp = &w_s[ic*16*56 + oc*56 + ky*8];
            float4 wa = *(const float4*)wp; float4 wb = *(const float4*)(wp+4);
            float wk[7] = {wa.x,wa.y,wa.z,wa.w,wb.x,wb.y,wb.z};
            #pragma unroll
            for (int kx = 0; kx < 7; kx++)
              #pragma unroll
              for (int j = 0; j < 4; j++)
                acc[oc][j] += iv[2*j+kx]*wk[kx];
          }
        }
      }
    }
  }
  if (act){
    int cr = r0 + r;
    for (int oc = 0; oc < 16; oc++)
      for (int j = 0; j < 4; j++){
        int c = c0+j;
        if (c < 49)
          conv2out[((n*64 + ocbase+oc)*49 + cr)*49 + c] =
            __float2bfloat16(fmaxf(acc[oc][j], 0.f));
      }
  }
}

// ---------- K3: maxpool2 -> pool2 bf16 [CHUNK,64,45,45]
__global__ __launch_bounds__(256) void k3_pool2(
    const bf16* __restrict__ cin, bf16* __restrict__ pout)
{
  int idx = blockIdx.x*256 + threadIdx.x;          // CHUNK*64*45*45 = 8,294,400
  int px = idx % 45; int t = idx/45; int py = t % 45; int ch = t/45;  // ch < CHUNK*64
  float m = -1e30f;
  const bf16* base = cin + (long)ch*2401;
  for (int dy = 0; dy < 7; dy++){
    int cy = py-1+dy; if (cy < 0 || cy > 48) continue;
    for (int dx = 0; dx < 7; dx++){
      int cx = px-1+dx; if (cx < 0 || cx > 48) continue;
      m = fmaxf(m, __bfloat162float(base[cy*49+cx]));
    }
  }
  pout[idx] = __float2bfloat16(m);
}

// ---------- K4: conv3(64->64,7x7,s2) + ReLU -> conv3out bf16 [CHUNK,64,20,20]
__global__ __launch_bounds__(256) void k4_conv3(
    const bf16* __restrict__ pool2, const float* __restrict__ w,
    bf16* __restrict__ conv3out)
{
  __shared__ __align__(16) float in_s[2*45*48];
  __shared__ __align__(16) float w_s[2*32*56];
  const int ocg = blockIdx.x;          // 0..1 (32 oc each)
  const int n = blockIdx.y;            // local patch
  const int half = threadIdx.x >> 7;   // 16-oc half within block
  const int t = threadIdx.x & 127;
  const int g = t % 5, r = t / 5;      // 5 col-groups x 20 rows (r<20 active)
  const int c0 = g*4;
  const bool act = (r < 20);
  float acc[16][4] = {};
  for (int ic0 = 0; ic0 < 64; ic0 += 2){
    __syncthreads();
    for (int idx = threadIdx.x; idx < 2*45*48; idx += 256){
      int ic = idx/(45*48); int rem = idx - ic*(45*48);
      int rr = rem/48, c = rem - rr*48;
      in_s[idx] = (c < 45) ?
        __bfloat162float(pool2[((n*64 + ic0+ic)*45 + rr)*45 + c]) : 0.f;
    }
    for (int idx = threadIdx.x; idx < 2*32*56; idx += 256){
      int ic = idx/(32*56); int rem = idx - ic*(32*56);
      int oc = rem/56; int k = rem - oc*56; int ky = k>>3, kx = k&7;
      w_s[idx] = (kx < 7) ? w[((ocg*32+oc)*64 + ic0+ic)*49 + ky*7 + kx] : 0.f;
    }
    __syncthreads();
    if (act){
      for (int ic = 0; ic < 2; ic++){
        for (int ky = 0; ky < 7; ky++){
          const float* ip = &in_s[ic*45*48 + (2*r+ky)*48 + 2*c0];
          float iv[13];
          #pragma unroll
          for (int i = 0; i < 13; i++) iv[i] = ip[i];
          #pragma unroll
          for (int oc = 0; oc < 16; oc++){
            const float* wp = &w_s[ic*32*56 + (half*16+oc)*56 + ky*8];
            float4 wa = *(const float4*)wp; float4 wb = *(const float4*)(wp+4);
            float wk[7] = {wa.x,wa.y,wa.z,wa.w,wb.x,wb.y,wb.z};
            #pragma unroll
            for (int kx = 0; kx < 7; kx++)
              #pragma unroll
              for (int j = 0; j < 4; j++)
                acc[oc][j] += iv[2*j+kx]*wk[kx];
          }
        }
      }
    }
  }
  if (act){
    int goc0 = ocg*32 + half*16;
    for (int oc = 0; oc < 16; oc++)
      for (int j = 0; j < 4; j++)
        conv3out[((n*64 + goc0+oc)*20 + r)*20 + c0+j] =
          __float2bfloat16(fmaxf(acc[oc][j], 0.f));
  }
}

// ---------- K5: maxpool3 -> feat bf16 [256,16384] (c,p1,p2 flatten order)
__global__ __launch_bounds__(256) void k5_pool3(
    const bf16* __restrict__ cin, bf16* __restrict__ feat, int n_base)
{
  int idx = blockIdx.x*256 + threadIdx.x;          // CHUNK*64*256 = 1,048,576
  int px = idx & 15; int t = idx >> 4; int py = t & 15; int ch = t >> 4; // ch < CHUNK*64
  float m = -1e30f;
  const bf16* base = cin + (long)ch*400;
  for (int dy = 0; dy < 7; dy++){
    int cy = py-1+dy; if (cy < 0 || cy > 19) continue;
    for (int dx = 0; dx < 7; dx++){
      int cx = px-1+dx; if (cx < 0 || cx > 19) continue;
      m = fmaxf(m, __bfloat162float(base[cy*20+cx]));
    }
  }
  int n_local = ch >> 6, c_local = ch & 63;
  feat[(long)(n_base + n_local)*16384 + c_local*256 + py*16 + px] = __float2bfloat16(m);
}

// ---------- K6a: init x[272,512] = cls/pos (row%17==0) or flat_b+pos
__global__ __launch_bounds__(256) void k6_init_x(
    const float* __restrict__ cls, const float* __restrict__ pos,
    const float* __restrict__ flat_b, float* __restrict__ x)
{
  int idx = blockIdx.x*256 + threadIdx.x;          // 139,264
  int d = idx & 511; int row = idx >> 9;
  int tt = row % 17;
  x[idx] = (tt == 0) ? (cls[d] + pos[d]) : (flat_b[d] + pos[tt*512 + d]);
}

// ---------- K6b: feat[256,16384](bf16) @ flat_w[16384,512] -> atomicAdd into x rows
__global__ __launch_bounds__(256) void k6_flat_gemm(
    const bf16* __restrict__ feat, const float* __restrict__ W,
    float* __restrict__ x)
{
  __shared__ float A_s[32][33];
  __shared__ __align__(16) float W_s[32][68];
  const int m0 = blockIdx.x*32, n0 = blockIdx.y*64, ks = blockIdx.z;
  const int r = threadIdx.x>>4, c0 = (threadIdx.x&15)*4;
  float acc0[4] = {}, acc1[4] = {};
  for (int kt = 0; kt < 64; kt++){
    int k0 = ks*2048 + kt*32;
    __syncthreads();
    for (int i = 0; i < 4; i++){ int id = threadIdx.x + i*256; int rr = id>>5, kk = id&31;
      A_s[rr][kk] = __bfloat162float(feat[(long)(m0+rr)*16384 + k0+kk]); }
    for (int i = 0; i < 8; i++){ int id = threadIdx.x + i*256; int kk = id>>6, c = id&63;
      W_s[kk][c] = W[(long)(k0+kk)*512 + n0+c]; }
    __syncthreads();
    #pragma unroll
    for (int kk = 0; kk < 32; kk++){
      float a0 = A_s[r][kk], a1 = A_s[r+16][kk];
      float4 w4 = *(const float4*)&W_s[kk][c0];
      acc0[0]+=a0*w4.x; acc0[1]+=a0*w4.y; acc0[2]+=a0*w4.z; acc0[3]+=a0*w4.w;
      acc1[0]+=a1*w4.x; acc1[1]+=a1*w4.y; acc1[2]+=a1*w4.z; acc1[3]+=a1*w4.w;
    }
  }
  int ma = m0+r, mb = m0+r+16;
  int rowa = (ma>>4)*17 + 1 + (ma&15);
  int rowb = (mb>>4)*17 + 1 + (mb&15);
  for (int j = 0; j < 4; j++){
    atomicAdd(&x[rowa*512 + n0+c0+j], acc0[j]);
    atomicAdd(&x[rowb*512 + n0+c0+j], acc1[j]);
  }
}

// ---------- LayerNorm over 512 elements, one block per row
__global__ __launch_bounds__(256) void ln_kernel(
    const float* __restrict__ in, const float* __restrict__ g,
    const float* __restrict__ b, float* __restrict__ out,
    int in_stride, int out_stride)
{
  int row = blockIdx.x;
  const float* p = in + (long)row*in_stride;
  float v0 = p[threadIdx.x], v1 = p[threadIdx.x+256];
  __shared__ float red[4]; __shared__ float stat;
  float s = v0+v1;
  #pragma unroll
  for (int o = 32; o >= 1; o >>= 1) s += __shfl_down(s, o);
  int lane = threadIdx.x & 63, wv = threadIdx.x >> 6;
  if (lane == 0) red[wv] = s;
  __syncthreads();
  if (threadIdx.x == 0) stat = (red[0]+red[1]+red[2]+red[3])*(1.0f/512.0f);
  __syncthreads();
  float m = stat;
  float d0 = v0-m, d1 = v1-m;
  float q = d0*d0 + d1*d1;
  #pragma unroll
  for (int o = 32; o >= 1; o >>= 1) q += __shfl_down(q, o);
  __syncthreads();
  if (lane == 0) red[wv] = q;
  __syncthreads();
  if (threadIdx.x == 0) stat = rsqrtf((red[0]+red[1]+red[2]+red[3])*(1.0f/512.0f) + 1e-5f);
  __syncthreads();
  float rstd = stat;
  out[(long)row*out_stride + threadIdx.x]     = d0*rstd*g[threadIdx.x]     + b[threadIdx.x];
  out[(long)row*out_stride + threadIdx.x+256] = d1*rstd*g[threadIdx.x+256] + b[threadIdx.x+256];
}

// ---------- Generic small GEMM: out = [res +] act(A@W + bias). BM=16,BN=64,BK=32
__global__ __launch_bounds__(256) void gemm_rows(
    const float* __restrict__ A, const float* __restrict__ W,
    const float* __restrict__ bias, const float* __restrict__ res,
    float* __restrict__ out, int M, int N, int K, int dogelu)
{
  __shared__ float A_s[16][33];
  __shared__ __align__(16) float W_s[32][68];
  const int m0 = blockIdx.x*16, n0 = blockIdx.y*64;
  const int r = threadIdx.x>>4, c0 = (threadIdx.x&15)*4;
  float acc[4] = {};
  for (int k0 = 0; k0 < K; k0 += 32){
    __syncthreads();
    for (int i = 0; i < 2; i++){ int id = threadIdx.x + i*256; int rr = id>>5, kk = id&31;
      A_s[rr][kk] = (m0+rr < M) ? A[(long)(m0+rr)*K + k0+kk] : 0.f; }
    for (int i = 0; i < 8; i++){ int id = threadIdx.x + i*256; int kk = id>>6, c = id&63;
      W_s[kk][c] = (n0+c < N) ? W[(long)(k0+kk)*N + n0+c] : 0.f; }
    __syncthreads();
    #pragma unroll
    for (int kk = 0; kk < 32; kk++){
      float a = A_s[r][kk];
      float4 w4 = *(const float4*)&W_s[kk][c0];
      acc[0]+=a*w4.x; acc[1]+=a*w4.y; acc[2]+=a*w4.z; acc[3]+=a*w4.w;
    }
  }
  if (m0+r < M){
    int row = m0+r;
    for (int j = 0; j < 4; j++){
      int c = n0+c0+j;
      if (c < N){
        float v = acc[j];
        if (bias) v += bias[c];
        if (dogelu) v = 0.5f*v*(1.0f + erff(v*0.70710678118654752f));
        if (res) v += res[(long)row*N + c];
        out[(long)row*N + c] = v;
      }
    }
  }
}

// ---------- Attention: one block per (b,h). N=17, DH=64.
__global__ __launch_bounds__(128) void attn_kernel(
    const float* __restrict__ qkv, float* __restrict__ obuf)
{
  const int b = blockIdx.x >> 3, h = blockIdx.x & 7;
  __shared__ float q_s[17][65], k_s[17][65], v_s[17][65], s_s[17][18];
  for (int idx = threadIdx.x; idx < 17*64; idx += 128){
    int i = idx>>6, d = idx&63;
    const float* base = qkv + (long)(b*17+i)*1536 + h*64 + d;
    q_s[i][d] = base[0]; k_s[i][d] = base[512]; v_s[i][d] = base[1024];
  }
  __syncthreads();
  for (int idx = threadIdx.x; idx < 289; idx += 128){
    int i = idx/17, j = idx - i*17;
    float s = 0.f;
    for (int d = 0; d < 64; d++) s += q_s[i][d]*k_s[j][d];
    s_s[i][j] = s*0.125f;
  }
  __syncthreads();
  if (threadIdx.x < 17){
    int i = threadIdx.x;
    float m = -1e30f;
    for (int j = 0; j < 17; j++) m = fmaxf(m, s_s[i][j]);
    float sum = 0.f;
    for (int j = 0; j < 17; j++){ float e = expf(s_s[i][j]-m); s_s[i][j] = e; sum += e; }
    float inv = 1.0f/sum;
    for (int j = 0; j < 17; j++) s_s[i][j] *= inv;
  }
  __syncthreads();
  for (int idx = threadIdx.x; idx < 17*64; idx += 128){
    int i = idx>>6, d = idx&63;
    float o = 0.f;
    for (int j = 0; j < 17; j++) o += s_s[i][j]*v_s[j][d];
    obuf[(long)(b*17+i)*512 + h*64 + d] = o;
  }
}

// ============================================================================
extern "C" void kernel_launch(void* const* d_in, const int* in_sizes, int n_in,
                              void* d_out, int out_size, void* d_ws, size_t ws_size,
                              hipStream_t stream) {
  const float* img      = (const float*)d_in[0];
  const float* conv1_w  = (const float*)d_in[1];
  const float* conv2_w  = (const float*)d_in[2];
  const float* conv3_w  = (const float*)d_in[3];
  const float* flat_w   = (const float*)d_in[4];
  const float* flat_b   = (const float*)d_in[5];
  const float* cls_tok  = (const float*)d_in[6];
  const float* pos_emb  = (const float*)d_in[7];
  const float* ln1_g    = (const float*)d_in[8];
  const float* ln1_b    = (const float*)d_in[9];
  const float* qkv_w    = (const float*)d_in[10];
  const float* out_w    = (const float*)d_in[11];
  const float* out_b    = (const float*)d_in[12];
  const float* ln2_g    = (const float*)d_in[13];
  const float* ln2_b    = (const float*)d_in[14];
  const float* ff1_w    = (const float*)d_in[15];
  const float* ff1_b    = (const float*)d_in[16];
  const float* ff2_w    = (const float*)d_in[17];
  const float* ff2_b    = (const float*)d_in[18];
  const float* hln_g    = (const float*)d_in[19];
  const float* hln_b    = (const float*)d_in[20];
  const float* head_w   = (const float*)d_in[21];
  const float* head_b   = (const float*)d_in[22];

  char* ws = (char*)d_ws;
  size_t off = 0;
  auto alloc = [&](size_t bytes) -> void* {
    void* p = ws + off; off += (bytes + 255) & ~(size_t)255; return p;
  };
  // Chunk-local CNN buffers (CHUNK=64 patches)
  bf16* pool1    = (bf16*)alloc((size_t)CHUNK*32*103*103*2);  // 43.5 MB
  bf16* conv2out = (bf16*)alloc((size_t)CHUNK*64*49*49*2);    // 19.7 MB
  bf16* pool2    = (bf16*)alloc((size_t)CHUNK*64*45*45*2);    // 16.6 MB
  bf16* conv3out = (bf16*)alloc((size_t)CHUNK*64*400*2);      //  3.3 MB
  // Persistent buffers
  bf16* feat     = (bf16*)alloc((size_t)256*16384*2);         //  8.4 MB
  float* x       = (float*)alloc((size_t)139264*4);           // 272x512
  float* h       = (float*)alloc((size_t)139264*4);
  float* qkvb    = (float*)alloc((size_t)417792*4);           // 272x1536
  float* obuf    = (float*)alloc((size_t)139264*4);
  float* ffbuf   = (float*)alloc((size_t)557056*4);           // 272x2048
  float* hcls    = (float*)alloc((size_t)8192*4);             // 16x512
  (void)ws_size; (void)in_sizes; (void)n_in; (void)out_size;

  // CNN stem, 4 chunks of 64 patches
  for (int cb = 0; cb < 256; cb += CHUNK){
    k1_conv1_pool<<<dim3(13,CHUNK), 256, 0, stream>>>(img, conv1_w, pool1, cb);
    k2_conv2     <<<dim3(12,CHUNK), 256, 0, stream>>>(pool1, conv2_w, conv2out);
    k3_pool2     <<<(CHUNK*64*45*45)/256, 256, 0, stream>>>(conv2out, pool2);
    k4_conv3     <<<dim3(2,CHUNK),  256, 0, stream>>>(pool2, conv3_w, conv3out);
    k5_pool3     <<<(CHUNK*64*256)/256, 256, 0, stream>>>(conv3out, feat, cb);
  }

  // Flatten projection + token assembly
  k6_init_x    <<<544,          256, 0, stream>>>(cls_tok, pos_emb, flat_b, x);
  k6_flat_gemm <<<dim3(8,8,8),  256, 0, stream>>>(feat, flat_w, x);

  // Transformer layers
  for (int l = 0; l < 6; l++){
    ln_kernel<<<272, 256, 0, stream>>>(x, ln1_g + l*512, ln1_b + l*512, h, 512, 512);
    gemm_rows<<<dim3(17,24), 256, 0, stream>>>(h, qkv_w + (size_t)l*786432,
                                               nullptr, nullptr, qkvb, 272, 1536, 512, 0);
    attn_kernel<<<128, 128, 0, stream>>>(qkvb, obuf);
    gemm_rows<<<dim3(17,8), 256, 0, stream>>>(obuf, out_w + (size_t)l*262144,
                                              out_b + l*512, x, x, 272, 512, 512, 0);
    ln_kernel<<<272, 256, 0, stream>>>(x, ln2_g + l*512, ln2_b + l*512, h, 512, 512);
    gemm_rows<<<dim3(17,32), 256, 0, stream>>>(h, ff1_w + (size_t)l*1048576,
                                               ff1_b + l*2048, nullptr, ffbuf, 272, 2048, 512, 1);
    gemm_rows<<<dim3(17,8), 256, 0, stream>>>(ffbuf, ff2_w + (size_t)l*1048576,
                                              ff2_b + l*512, x, x, 272, 512, 2048, 0);
  }

  // Head
  ln_kernel<<<16, 256, 0, stream>>>(x, hln_g, hln_b, hcls, 17*512, 512);
  gemm_rows<<<dim3(1,16), 256, 0, stream>>>(hcls, head_w, head_b, nullptr,
                                            (float*)d_out, 16, 1000, 512, 0);
}

// Round 3
// 5568.780 us; speedup vs baseline: 1.7960x; 1.7960x over previous
//
#include <hip/hip_runtime.h>
#include <hip/hip_bf16.h>

// ============================================================================
// HybridViT forward. Round 3: conv2/conv3 -> bf16 MFMA implicit GEMM.
//  - NHWC intermediates; parity-split LDS (stride-2 gather -> stride-1),
//    ic padded 32->40 (20-word pixel stride -> 2-way bank alias = free).
//  - A-frags (weights, repacked [ky][kx][oc][ic] bf16) loaded from global
//    (L2-resident); LDS holds input only -> 2-4 blocks/CU.
//  - k1-k3 chunked (CHUNK=64); pool2 kept full so k4 runs 512 blocks at once.
// ============================================================================

typedef __hip_bfloat16 bf16;
typedef __attribute__((ext_vector_type(8))) short short8;
typedef __attribute__((ext_vector_type(4))) float floatx4;

#define CHUNK 64

// ---------- weight prep: conv2_w fp32 [64][32][7][7] -> bf16 [ky*7+kx][64][32]
__global__ __launch_bounds__(256) void prep_w2(const float* __restrict__ w,
                                               bf16* __restrict__ w2b)
{
  int idx = blockIdx.x*256 + threadIdx.x;     // 49*64*32 = 100352
  if (idx >= 49*64*32) return;
  int ic = idx & 31; int t = idx >> 5; int oc = t & 63; int kk = t >> 6;
  int ky = kk/7, kx = kk - ky*7;
  w2b[idx] = __float2bfloat16(w[((oc*32+ic)*7+ky)*7+kx]);
}

// ---------- weight prep: conv3_w fp32 [64][64][7][7] -> bf16 [ky][kc][kx][64][32]
__global__ __launch_bounds__(256) void prep_w3(const float* __restrict__ w,
                                               bf16* __restrict__ w3b)
{
  int idx = blockIdx.x*256 + threadIdx.x;     // 49*2*64*32 = 200704
  if (idx >= 49*2*64*32) return;
  int ic_l = idx & 31; int t = idx >> 5; int oc = t & 63; int t2 = t >> 6;
  int kx = t2 % 7; int t3 = t2 / 7; int kc = t3 & 1; int ky = t3 >> 1;
  w3b[idx] = __float2bfloat16(w[((oc*64 + kc*32 + ic_l)*7+ky)*7+kx]);
}

// ---------- K1: patchify + conv1(1->32,7x7,s2) + ReLU + pool -> pool1 NHWC [CHUNK,103,103,32]
__global__ __launch_bounds__(256) void k1_conv1_pool(
    const float* __restrict__ img, const float* __restrict__ w,
    bf16* __restrict__ pool1, int n_base)
{
  __shared__ __align__(16) float in_s[33*224];
  __shared__ __align__(16) float conv_s[4*14*112];
  __shared__ __align__(16) float w_s[32*56];
  const int strip = blockIdx.x;        // 0..12
  const int n = blockIdx.y;            // local patch
  const int ng = n_base + n;
  const int p0 = strip*8;
  const int PR = min(8, 103-p0);
  const int cr0 = max(p0-1, 0);
  const int cr1 = min(p0+PR+4, 106);
  const int CR = cr1-cr0+1;
  const int ir0 = 2*cr0;
  const int IR = 2*CR+5;
  const int b = ng>>4, gh = (ng>>2)&3, gw = ng&3;
  const float* ibase = img + b*774400 + (gh*220)*880 + gw*220;

  for (int idx = threadIdx.x; idx < IR*224; idx += 256){
    int r = idx/224, c = idx - r*224;
    in_s[idx] = (c < 220) ? ibase[(ir0+r)*880 + c] : 0.f;
  }
  for (int idx = threadIdx.x; idx < 32*56; idx += 256){
    int oc = idx/56, k = idx - oc*56; int ky = k>>3, kx = k&7;
    w_s[idx] = (kx < 7 && ky < 7) ? w[oc*49 + ky*7 + kx] : 0.f;
  }
  __syncthreads();

  for (int grp = 0; grp < 8; grp++){
    for (int t = threadIdx.x; t < CR*27; t += 256){
      int r = t/27, g = t - r*27; int c0 = g*4;
      float acc[4][4] = {};
      for (int ky = 0; ky < 7; ky++){
        const float* ip = &in_s[(2*r+ky)*224 + 2*c0];
        float iv[13];
        #pragma unroll
        for (int i = 0; i < 13; i++) iv[i] = ip[i];
        #pragma unroll
        for (int oc = 0; oc < 4; oc++){
          const float* wp = &w_s[(grp*4+oc)*56 + ky*8];
          float4 wa = *(const float4*)wp;
          float4 wb = *(const float4*)(wp+4);
          float wk[7] = {wa.x,wa.y,wa.z,wa.w,wb.x,wb.y,wb.z};
          #pragma unroll
          for (int kx = 0; kx < 7; kx++)
            #pragma unroll
            for (int j = 0; j < 4; j++)
              acc[oc][j] += iv[2*j+kx]*wk[kx];
        }
      }
      #pragma unroll
      for (int oc = 0; oc < 4; oc++)
        #pragma unroll
        for (int j = 0; j < 4; j++)
          conv_s[(oc*14 + r)*112 + c0 + j] = fmaxf(acc[oc][j], 0.f);
    }
    __syncthreads();
    for (int t = threadIdx.x; t < PR*103; t += 256){
      int pr = t/103, pc = t - pr*103;
      int py = p0 + pr;
      float m0v=-1e30f, m1v=-1e30f, m2v=-1e30f, m3v=-1e30f;
      for (int dy = 0; dy < 7; dy++){
        int rr = py-1+dy;
        if (rr < 0 || rr > 106) continue;
        int lr = rr - cr0;
        for (int dx = 0; dx < 7; dx++){
          int cc = pc-1+dx;
          if (cc < 0 || cc > 106) continue;
          m0v = fmaxf(m0v, conv_s[(0*14+lr)*112 + cc]);
          m1v = fmaxf(m1v, conv_s[(1*14+lr)*112 + cc]);
          m2v = fmaxf(m2v, conv_s[(2*14+lr)*112 + cc]);
          m3v = fmaxf(m3v, conv_s[(3*14+lr)*112 + cc]);
        }
      }
      // NHWC write: 4 consecutive channels
      int obase = ((n*103 + py)*103 + pc)*32 + grp*4;
      pool1[obase+0] = __float2bfloat16(m0v);
      pool1[obase+1] = __float2bfloat16(m1v);
      pool1[obase+2] = __float2bfloat16(m2v);
      pool1[obase+3] = __float2bfloat16(m3v);
    }
    __syncthreads();
  }
}

// ---------- K2: conv2 MFMA implicit GEMM. pool1 NHWC -> conv2out NHWC [CHUNK,49,49,64]
// block = 256 thr (4 waves); block covers 256 pixels x 64 oc; wave = 4 pixtiles x 4 octiles.
__global__ __launch_bounds__(256) void k2_conv2(
    const bf16* __restrict__ pool1,   // [CHUNK][103][103][32]
    const bf16* __restrict__ w2b,     // [49][64][32]
    bf16* __restrict__ conv2out)      // [CHUNK][49][49][64]
{
  __shared__ __align__(16) bf16 in_s[7*2*52*40];   // [r][par][52][40] = 58240 B
  const int n = blockIdx.y, pb = blockIdx.x;       // pb 0..9
  const int wv = threadIdx.x >> 6, lane = threadIdx.x & 63;
  const int li = lane & 15, lg = lane >> 4;
  const int p0 = pb*256;
  const int y0 = p0/49;

  int pyv[4], pxv[4], poff[4]; bool pmask[4];
  #pragma unroll
  for (int t = 0; t < 4; t++){
    int p = p0 + wv*64 + t*16 + li;
    pmask[t] = (p <= 2400);
    int pc = min(p, 2400);
    int yy = pc/49, xx = pc - yy*49;
    pyv[t] = yy; pxv[t] = xx;
    poff[t] = ((yy - y0)*2*52 + xx)*40;   // parity-even base
  }
  floatx4 acc[4][4];
  #pragma unroll
  for (int a = 0; a < 4; a++)
    #pragma unroll
    for (int t = 0; t < 4; t++) acc[a][t] = (floatx4){0.f,0.f,0.f,0.f};

  for (int ky = 0; ky < 7; ky++){
    __syncthreads();
    // stage rows 2(y0+j)+ky, j=0..6 : [r][c&1][c>>1][ic0..31 pad40]
    for (int idx = threadIdx.x; idx < 7*103*4; idx += 256){
      int q = idx & 3; int t2 = idx >> 2; int c = t2 % 103; int r = t2/103;
      int gr = min(2*(y0+r)+ky, 102);
      const bf16* src = pool1 + (((long)n*103 + gr)*103 + c)*32 + q*8;
      bf16* dst = &in_s[((r*2 + (c&1))*52 + (c>>1))*40 + q*8];
      *(int4*)dst = *(const int4*)src;
    }
    __syncthreads();
    for (int kx = 0; kx < 7; kx++){
      short8 a[4];
      const bf16* wp = w2b + (ky*7+kx)*64*32;
      #pragma unroll
      for (int ot = 0; ot < 4; ot++)
        a[ot] = *(const short8*)(wp + (ot*16 + li)*32 + lg*8);
      int koff = ((kx&1)*52 + (kx>>1))*40 + lg*8;
      #pragma unroll
      for (int t = 0; t < 4; t++){
        short8 bfr = *(const short8*)(&in_s[poff[t] + koff]);
        #pragma unroll
        for (int ot = 0; ot < 4; ot++)
          acc[ot][t] = __builtin_amdgcn_mfma_f32_16x16x32_bf16(a[ot], bfr, acc[ot][t], 0, 0, 0);
      }
    }
  }
  // store: C layout col=lane&15 (pixel), row=(lane>>4)*4+v (oc)
  #pragma unroll
  for (int t = 0; t < 4; t++){
    if (!pmask[t]) continue;
    bf16* dst = conv2out + (((long)n*49 + pyv[t])*49 + pxv[t])*64 + lg*4;
    #pragma unroll
    for (int ot = 0; ot < 4; ot++){
      union { bf16 h[4]; uint2 u; } pk;
      #pragma unroll
      for (int v = 0; v < 4; v++)
        pk.h[v] = __float2bfloat16(fmaxf(acc[ot][t][v], 0.f));
      *(uint2*)(dst + ot*16) = pk.u;
    }
  }
}

// ---------- K3: maxpool2 NHWC -> pool2 NHWC [256,45,45,64] (writes at n_base)
__global__ __launch_bounds__(256) void k3_pool2(
    const bf16* __restrict__ cin, bf16* __restrict__ pout, int n_base)
{
  int idx = blockIdx.x*256 + threadIdx.x;          // CHUNK*45*45*64
  int c = idx & 63; int t = idx >> 6; int px = t % 45; int t2 = t/45;
  int py = t2 % 45; int nl = t2/45;
  float m = -1e30f;
  const bf16* base = cin + (long)nl*2401*64 + c;
  for (int dy = 0; dy < 7; dy++){
    int cy = py-1+dy; if (cy < 0 || cy > 48) continue;
    for (int dx = 0; dx < 7; dx++){
      int cx = px-1+dx; if (cx < 0 || cx > 48) continue;
      m = fmaxf(m, __bfloat162float(base[(cy*49+cx)*64]));
    }
  }
  pout[(long)n_base*129600 + idx] = __float2bfloat16(m);
}

// ---------- K4: conv3 MFMA implicit GEMM. pool2 NHWC [256,45,45,64] -> conv3out NHWC [256,20,20,64]
// grid (2, 256): pb = half (200 px), n = patch. block 256 thr; wave = 4 pixtiles x 4 octiles.
__global__ __launch_bounds__(256) void k4_conv3(
    const bf16* __restrict__ pool2,
    const bf16* __restrict__ w3b,     // [ky][kc][kx][64][32]
    bf16* __restrict__ conv3out)
{
  __shared__ __align__(16) bf16 in_s[10*2*24*40];  // 38400 B
  const int n = blockIdx.y, pb = blockIdx.x;       // pb 0..1
  const int wv = threadIdx.x >> 6, lane = threadIdx.x & 63;
  const int li = lane & 15, lg = lane >> 4;
  const int y0 = pb*10;

  int pyv[4], pxv[4], poff[4]; bool pmask[4];
  #pragma unroll
  for (int t = 0; t < 4; t++){
    int pl = wv*64 + t*16 + li;          // 0..255
    pmask[t] = (pl < 200);
    int p = pb*200 + min(pl, 199);       // clamp within block's rows
    int yy = p/20, xx = p - yy*20;
    pyv[t] = yy; pxv[t] = xx;
    poff[t] = ((yy - y0)*2*24 + xx)*40;
  }
  floatx4 acc[4][4];
  #pragma unroll
  for (int a = 0; a < 4; a++)
    #pragma unroll
    for (int t = 0; t < 4; t++) acc[a][t] = (floatx4){0.f,0.f,0.f,0.f};

  for (int ky = 0; ky < 7; ky++){
    for (int kc = 0; kc < 2; kc++){
      __syncthreads();
      // stage rows 2(y0+j)+ky (j=0..9), ic half kc
      for (int idx = threadIdx.x; idx < 10*45*4; idx += 256){
        int q = idx & 3; int t2 = idx >> 2; int c = t2 % 45; int r = t2/45;
        int gr = 2*(y0+r)+ky;            // <= 44, always valid
        const bf16* src = pool2 + (((long)n*45 + gr)*45 + c)*64 + kc*32 + q*8;
        bf16* dst = &in_s[((r*2 + (c&1))*24 + (c>>1))*40 + q*8];
        *(int4*)dst = *(const int4*)src;
      }
      __syncthreads();
      for (int kx = 0; kx < 7; kx++){
        short8 a[4];
        const bf16* wp = w3b + ((ky*2+kc)*7 + kx)*64*32;
        #pragma unroll
        for (int ot = 0; ot < 4; ot++)
          a[ot] = *(const short8*)(wp + (ot*16 + li)*32 + lg*8);
        int koff = ((kx&1)*24 + (kx>>1))*40 + lg*8;
        #pragma unroll
        for (int t = 0; t < 4; t++){
          short8 bfr = *(const short8*)(&in_s[poff[t] + koff]);
          #pragma unroll
          for (int ot = 0; ot < 4; ot++)
            acc[ot][t] = __builtin_amdgcn_mfma_f32_16x16x32_bf16(a[ot], bfr, acc[ot][t], 0, 0, 0);
        }
      }
    }
  }
  #pragma unroll
  for (int t = 0; t < 4; t++){
    if (!pmask[t]) continue;
    bf16* dst = conv3out + (((long)n*20 + pyv[t])*20 + pxv[t])*64 + lg*4;
    #pragma unroll
    for (int ot = 0; ot < 4; ot++){
      union { bf16 h[4]; uint2 u; } pk;
      #pragma unroll
      for (int v = 0; v < 4; v++)
        pk.h[v] = __float2bfloat16(fmaxf(acc[ot][t][v], 0.f));
      *(uint2*)(dst + ot*16) = pk.u;
    }
  }
}

// ---------- K5: maxpool3 NHWC -> feat [256,16384] in (c,p1,p2) flatten order
__global__ __launch_bounds__(256) void k5_pool3(
    const bf16* __restrict__ cin, bf16* __restrict__ feat)
{
  int idx = blockIdx.x*256 + threadIdx.x;  // 256*16384; idx = n*16384 + c*256 + py*16 + px
  int px = idx & 15; int py = (idx>>4) & 15; int c = (idx>>8) & 63; int n = idx >> 14;
  float m = -1e30f;
  const bf16* base = cin + (long)n*400*64 + c;
  for (int dy = 0; dy < 7; dy++){
    int cy = py-1+dy; if (cy < 0 || cy > 19) continue;
    for (int dx = 0; dx < 7; dx++){
      int cx = px-1+dx; if (cx < 0 || cx > 19) continue;
      m = fmaxf(m, __bfloat162float(base[(cy*20+cx)*64]));
    }
  }
  feat[idx] = __float2bfloat16(m);
}

// ---------- K6a: init x[272,512]
__global__ __launch_bounds__(256) void k6_init_x(
    const float* __restrict__ cls, const float* __restrict__ pos,
    const float* __restrict__ flat_b, float* __restrict__ x)
{
  int idx = blockIdx.x*256 + threadIdx.x;
  int d = idx & 511; int row = idx >> 9;
  int tt = row % 17;
  x[idx] = (tt == 0) ? (cls[d] + pos[d]) : (flat_b[d] + pos[tt*512 + d]);
}

// ---------- K6b: feat @ flat_w -> atomicAdd into x
__global__ __launch_bounds__(256) void k6_flat_gemm(
    const bf16* __restrict__ feat, const float* __restrict__ W,
    float* __restrict__ x)
{
  __shared__ float A_s[32][33];
  __shared__ __align__(16) float W_s[32][68];
  const int m0 = blockIdx.x*32, n0 = blockIdx.y*64, ks = blockIdx.z;
  const int r = threadIdx.x>>4, c0 = (threadIdx.x&15)*4;
  float acc0[4] = {}, acc1[4] = {};
  for (int kt = 0; kt < 64; kt++){
    int k0 = ks*2048 + kt*32;
    __syncthreads();
    for (int i = 0; i < 4; i++){ int id = threadIdx.x + i*256; int rr = id>>5, kk = id&31;
      A_s[rr][kk] = __bfloat162float(feat[(long)(m0+rr)*16384 + k0+kk]); }
    for (int i = 0; i < 8; i++){ int id = threadIdx.x + i*256; int kk = id>>6, c = id&63;
      W_s[kk][c] = W[(long)(k0+kk)*512 + n0+c]; }
    __syncthreads();
    #pragma unroll
    for (int kk = 0; kk < 32; kk++){
      float a0 = A_s[r][kk], a1 = A_s[r+16][kk];
      float4 w4 = *(const float4*)&W_s[kk][c0];
      acc0[0]+=a0*w4.x; acc0[1]+=a0*w4.y; acc0[2]+=a0*w4.z; acc0[3]+=a0*w4.w;
      acc1[0]+=a1*w4.x; acc1[1]+=a1*w4.y; acc1[2]+=a1*w4.z; acc1[3]+=a1*w4.w;
    }
  }
  int ma = m0+r, mb = m0+r+16;
  int rowa = (ma>>4)*17 + 1 + (ma&15);
  int rowb = (mb>>4)*17 + 1 + (mb&15);
  for (int j = 0; j < 4; j++){
    atomicAdd(&x[rowa*512 + n0+c0+j], acc0[j]);
    atomicAdd(&x[rowb*512 + n0+c0+j], acc1[j]);
  }
}

// ---------- LayerNorm over 512
__global__ __launch_bounds__(256) void ln_kernel(
    const float* __restrict__ in, const float* __restrict__ g,
    const float* __restrict__ b, float* __restrict__ out,
    int in_stride, int out_stride)
{
  int row = blockIdx.x;
  const float* p = in + (long)row*in_stride;
  float v0 = p[threadIdx.x], v1 = p[threadIdx.x+256];
  __shared__ float red[4]; __shared__ float stat;
  float s = v0+v1;
  #pragma unroll
  for (int o = 32; o >= 1; o >>= 1) s += __shfl_down(s, o);
  int lane = threadIdx.x & 63, wv = threadIdx.x >> 6;
  if (lane == 0) red[wv] = s;
  __syncthreads();
  if (threadIdx.x == 0) stat = (red[0]+red[1]+red[2]+red[3])*(1.0f/512.0f);
  __syncthreads();
  float m = stat;
  float d0 = v0-m, d1 = v1-m;
  float q = d0*d0 + d1*d1;
  #pragma unroll
  for (int o = 32; o >= 1; o >>= 1) q += __shfl_down(q, o);
  __syncthreads();
  if (lane == 0) red[wv] = q;
  __syncthreads();
  if (threadIdx.x == 0) stat = rsqrtf((red[0]+red[1]+red[2]+red[3])*(1.0f/512.0f) + 1e-5f);
  __syncthreads();
  float rstd = stat;
  out[(long)row*out_stride + threadIdx.x]     = d0*rstd*g[threadIdx.x]     + b[threadIdx.x];
  out[(long)row*out_stride + threadIdx.x+256] = d1*rstd*g[threadIdx.x+256] + b[threadIdx.x+256];
}

// ---------- Generic small GEMM: out = [res +] act(A@W + bias)
__global__ __launch_bounds__(256) void gemm_rows(
    const float* __restrict__ A, const float* __restrict__ W,
    const float* __restrict__ bias, const float* __restrict__ res,
    float* __restrict__ out, int M, int N, int K, int dogelu)
{
  __shared__ float A_s[16][33];
  __shared__ __align__(16) float W_s[32][68];
  const int m0 = blockIdx.x*16, n0 = blockIdx.y*64;
  const int r = threadIdx.x>>4, c0 = (threadIdx.x&15)*4;
  float acc[4] = {};
  for (int k0 = 0; k0 < K; k0 += 32){
    __syncthreads();
    for (int i = 0; i < 2; i++){ int id = threadIdx.x + i*256; int rr = id>>5, kk = id&31;
      A_s[rr][kk] = (m0+rr < M) ? A[(long)(m0+rr)*K + k0+kk] : 0.f; }
    for (int i = 0; i < 8; i++){ int id = threadIdx.x + i*256; int kk = id>>6, c = id&63;
      W_s[kk][c] = (n0+c < N) ? W[(long)(k0+kk)*N + n0+c] : 0.f; }
    __syncthreads();
    #pragma unroll
    for (int kk = 0; kk < 32; kk++){
      float a = A_s[r][kk];
      float4 w4 = *(const float4*)&W_s[kk][c0];
      acc[0]+=a*w4.x; acc[1]+=a*w4.y; acc[2]+=a*w4.z; acc[3]+=a*w4.w;
    }
  }
  if (m0+r < M){
    int row = m0+r;
    for (int j = 0; j < 4; j++){
      int c = n0+c0+j;
      if (c < N){
        float v = acc[j];
        if (bias) v += bias[c];
        if (dogelu) v = 0.5f*v*(1.0f + erff(v*0.70710678118654752f));
        if (res) v += res[(long)row*N + c];
        out[(long)row*N + c] = v;
      }
    }
  }
}

// ---------- Attention: one block per (b,h). N=17, DH=64.
__global__ __launch_bounds__(128) void attn_kernel(
    const float* __restrict__ qkv, float* __restrict__ obuf)
{
  const int b = blockIdx.x >> 3, h = blockIdx.x & 7;
  __shared__ float q_s[17][65], k_s[17][65], v_s[17][65], s_s[17][18];
  for (int idx = threadIdx.x; idx < 17*64; idx += 128){
    int i = idx>>6, d = idx&63;
    const float* base = qkv + (long)(b*17+i)*1536 + h*64 + d;
    q_s[i][d] = base[0]; k_s[i][d] = base[512]; v_s[i][d] = base[1024];
  }
  __syncthreads();
  for (int idx = threadIdx.x; idx < 289; idx += 128){
    int i = idx/17, j = idx - i*17;
    float s = 0.f;
    for (int d = 0; d < 64; d++) s += q_s[i][d]*k_s[j][d];
    s_s[i][j] = s*0.125f;
  }
  __syncthreads();
  if (threadIdx.x < 17){
    int i = threadIdx.x;
    float m = -1e30f;
    for (int j = 0; j < 17; j++) m = fmaxf(m, s_s[i][j]);
    float sum = 0.f;
    for (int j = 0; j < 17; j++){ float e = expf(s_s[i][j]-m); s_s[i][j] = e; sum += e; }
    float inv = 1.0f/sum;
    for (int j = 0; j < 17; j++) s_s[i][j] *= inv;
  }
  __syncthreads();
  for (int idx = threadIdx.x; idx < 17*64; idx += 128){
    int i = idx>>6, d = idx&63;
    float o = 0.f;
    for (int j = 0; j < 17; j++) o += s_s[i][j]*v_s[j][d];
    obuf[(long)(b*17+i)*512 + h*64 + d] = o;
  }
}

// ============================================================================
extern "C" void kernel_launch(void* const* d_in, const int* in_sizes, int n_in,
                              void* d_out, int out_size, void* d_ws, size_t ws_size,
                              hipStream_t stream) {
  const float* img      = (const float*)d_in[0];
  const float* conv1_w  = (const float*)d_in[1];
  const float* conv2_w  = (const float*)d_in[2];
  const float* conv3_w  = (const float*)d_in[3];
  const float* flat_w   = (const float*)d_in[4];
  const float* flat_b   = (const float*)d_in[5];
  const float* cls_tok  = (const float*)d_in[6];
  const float* pos_emb  = (const float*)d_in[7];
  const float* ln1_g    = (const float*)d_in[8];
  const float* ln1_b    = (const float*)d_in[9];
  const float* qkv_w    = (const float*)d_in[10];
  const float* out_w    = (const float*)d_in[11];
  const float* out_b    = (const float*)d_in[12];
  const float* ln2_g    = (const float*)d_in[13];
  const float* ln2_b    = (const float*)d_in[14];
  const float* ff1_w    = (const float*)d_in[15];
  const float* ff1_b    = (const float*)d_in[16];
  const float* ff2_w    = (const float*)d_in[17];
  const float* ff2_b    = (const float*)d_in[18];
  const float* hln_g    = (const float*)d_in[19];
  const float* hln_b    = (const float*)d_in[20];
  const float* head_w   = (const float*)d_in[21];
  const float* head_b   = (const float*)d_in[22];

  char* ws = (char*)d_ws;
  size_t off = 0;
  auto alloc = [&](size_t bytes) -> void* {
    void* p = ws + off; off += (bytes + 255) & ~(size_t)255; return p;
  };
  bf16* pool1    = (bf16*)alloc((size_t)CHUNK*103*103*32*2);  // 43.5 MB (chunk, NHWC)
  bf16* conv2out = (bf16*)alloc((size_t)CHUNK*49*49*64*2);    // 19.7 MB (chunk, NHWC)
  bf16* pool2    = (bf16*)alloc((size_t)256*45*45*64*2);      // 66.4 MB (full, NHWC)
  bf16* feat     = (bf16*)alloc((size_t)256*16384*2);         //  8.4 MB
  bf16* w2b      = (bf16*)alloc((size_t)49*64*32*2);
  bf16* w3b      = (bf16*)alloc((size_t)49*2*64*32*2);
  float* x       = (float*)alloc((size_t)139264*4);
  float* h       = (float*)alloc((size_t)139264*4);
  float* qkvb    = (float*)alloc((size_t)417792*4);
  float* obuf    = (float*)alloc((size_t)139264*4);
  float* ffbuf   = (float*)alloc((size_t)557056*4);
  float* hcls    = (float*)alloc((size_t)8192*4);
  // conv3out aliases pool1 (dead after last k2): 13.1 MB <= 43.5 MB
  bf16* conv3out = pool1;
  (void)ws_size; (void)in_sizes; (void)n_in; (void)out_size;

  prep_w2<<<392, 256, 0, stream>>>(conv2_w, w2b);
  prep_w3<<<784, 256, 0, stream>>>(conv3_w, w3b);

  // CNN stem: chunks for k1-k3 (pool2 written full), then k4/k5 over all patches
  for (int cb = 0; cb < 256; cb += CHUNK){
    k1_conv1_pool<<<dim3(13,CHUNK), 256, 0, stream>>>(img, conv1_w, pool1, cb);
    k2_conv2     <<<dim3(10,CHUNK), 256, 0, stream>>>(pool1, w2b, conv2out);
    k3_pool2     <<<(CHUNK*45*45*64)/256, 256, 0, stream>>>(conv2out, pool2, cb);
  }
  k4_conv3<<<dim3(2,256), 256, 0, stream>>>(pool2, w3b, conv3out);
  k5_pool3<<<16384, 256, 0, stream>>>(conv3out, feat);

  // Flatten projection + token assembly
  k6_init_x    <<<544,          256, 0, stream>>>(cls_tok, pos_emb, flat_b, x);
  k6_flat_gemm <<<dim3(8,8,8),  256, 0, stream>>>(feat, flat_w, x);

  // Transformer layers
  for (int l = 0; l < 6; l++){
    ln_kernel<<<272, 256, 0, stream>>>(x, ln1_g + l*512, ln1_b + l*512, h, 512, 512);
    gemm_rows<<<dim3(17,24), 256, 0, stream>>>(h, qkv_w + (size_t)l*786432,
                                               nullptr, nullptr, qkvb, 272, 1536, 512, 0);
    attn_kernel<<<128, 128, 0, stream>>>(qkvb, obuf);
    gemm_rows<<<dim3(17,8), 256, 0, stream>>>(obuf, out_w + (size_t)l*262144,
                                              out_b + l*512, x, x, 272, 512, 512, 0);
    ln_kernel<<<272, 256, 0, stream>>>(x, ln2_g + l*512, ln2_b + l*512, h, 512, 512);
    gemm_rows<<<dim3(17,32), 256, 0, stream>>>(h, ff1_w + (size_t)l*1048576,
                                               ff1_b + l*2048, nullptr, ffbuf, 272, 2048, 512, 1);
    gemm_rows<<<dim3(17,8), 256, 0, stream>>>(ffbuf, ff2_w + (size_t)l*1048576,
                                              ff2_b + l*512, x, x, 272, 512, 2048, 0);
  }

  // Head
  ln_kernel<<<16, 256, 0, stream>>>(x, hln_g, hln_b, hcls, 17*512, 512);
  gemm_rows<<<dim3(1,16), 256, 0, stream>>>(hcls, head_w, head_b, nullptr,
                                            (float*)d_out, 16, 1000, 512, 0);
}

// Round 4
// 4249.195 us; speedup vs baseline: 2.3538x; 1.3105x over previous
//
#include <hip/hip_runtime.h>
#include <hip/hip_bf16.h>

// ============================================================================
// HybridViT forward. Round 4: separable 7x7 maxpools (7+7 instead of 49),
// u16-bitwise bf16 max (valid: all pool inputs are post-ReLU >= 0).
//  - k5: in-LDS per-patch pool (was 441us channel-strided scalar loads).
//  - k3: two-pass global separable pool, int4 coalesced.
//  - k1: in-LDS separable pool (vertical tmp then horizontal).
// Convs (MFMA k2/k4) unchanged from round 3.
// ============================================================================

typedef __hip_bfloat16 bf16;
typedef __attribute__((ext_vector_type(8))) short short8;
typedef __attribute__((ext_vector_type(4))) float floatx4;

#define CHUNK 64

union U8 { int4 v; unsigned short s[8]; };
__device__ inline void umax8(U8& a, const U8& b){
  #pragma unroll
  for (int j = 0; j < 8; j++) a.s[j] = (a.s[j] > b.s[j]) ? a.s[j] : b.s[j];
}

// ---------- weight prep: conv2_w fp32 [64][32][7][7] -> bf16 [ky*7+kx][64][32]
__global__ __launch_bounds__(256) void prep_w2(const float* __restrict__ w,
                                               bf16* __restrict__ w2b)
{
  int idx = blockIdx.x*256 + threadIdx.x;     // 49*64*32 = 100352
  if (idx >= 49*64*32) return;
  int ic = idx & 31; int t = idx >> 5; int oc = t & 63; int kk = t >> 6;
  int ky = kk/7, kx = kk - ky*7;
  w2b[idx] = __float2bfloat16(w[((oc*32+ic)*7+ky)*7+kx]);
}

// ---------- weight prep: conv3_w fp32 [64][64][7][7] -> bf16 [ky][kc][kx][64][32]
__global__ __launch_bounds__(256) void prep_w3(const float* __restrict__ w,
                                               bf16* __restrict__ w3b)
{
  int idx = blockIdx.x*256 + threadIdx.x;     // 49*2*64*32 = 200704
  if (idx >= 49*2*64*32) return;
  int ic_l = idx & 31; int t = idx >> 5; int oc = t & 63; int t2 = t >> 6;
  int kx = t2 % 7; int t3 = t2 / 7; int kc = t3 & 1; int ky = t3 >> 1;
  w3b[idx] = __float2bfloat16(w[((oc*64 + kc*32 + ic_l)*7+ky)*7+kx]);
}

// ---------- K1: patchify + conv1(1->32,7x7,s2) + ReLU + separable pool
//              -> pool1 NHWC [CHUNK,103,103,32]
__global__ __launch_bounds__(256) void k1_conv1_pool(
    const float* __restrict__ img, const float* __restrict__ w,
    bf16* __restrict__ pool1, int n_base)
{
  __shared__ __align__(16) float in_s[33*224];
  __shared__ __align__(16) float conv_s[4*14*112];
  __shared__ __align__(16) float w_s[32*56];
  __shared__ __align__(16) float vtmp_s[4*8*108];   // vertical-max tmp
  const int strip = blockIdx.x;        // 0..12
  const int n = blockIdx.y;            // local patch
  const int ng = n_base + n;
  const int p0 = strip*8;
  const int PR = min(8, 103-p0);
  const int cr0 = max(p0-1, 0);
  const int cr1 = min(p0+PR+4, 106);
  const int CR = cr1-cr0+1;
  const int ir0 = 2*cr0;
  const int IR = 2*CR+5;
  const int b = ng>>4, gh = (ng>>2)&3, gw = ng&3;
  const float* ibase = img + b*774400 + (gh*220)*880 + gw*220;

  for (int idx = threadIdx.x; idx < IR*224; idx += 256){
    int r = idx/224, c = idx - r*224;
    in_s[idx] = (c < 220) ? ibase[(ir0+r)*880 + c] : 0.f;
  }
  for (int idx = threadIdx.x; idx < 32*56; idx += 256){
    int oc = idx/56, k = idx - oc*56; int ky = k>>3, kx = k&7;
    w_s[idx] = (kx < 7 && ky < 7) ? w[oc*49 + ky*7 + kx] : 0.f;
  }
  __syncthreads();

  for (int grp = 0; grp < 8; grp++){
    for (int t = threadIdx.x; t < CR*27; t += 256){
      int r = t/27, g = t - r*27; int c0 = g*4;
      float acc[4][4] = {};
      for (int ky = 0; ky < 7; ky++){
        const float* ip = &in_s[(2*r+ky)*224 + 2*c0];
        float iv[13];
        #pragma unroll
        for (int i = 0; i < 13; i++) iv[i] = ip[i];
        #pragma unroll
        for (int oc = 0; oc < 4; oc++){
          const float* wp = &w_s[(grp*4+oc)*56 + ky*8];
          float4 wa = *(const float4*)wp;
          float4 wb = *(const float4*)(wp+4);
          float wk[7] = {wa.x,wa.y,wa.z,wa.w,wb.x,wb.y,wb.z};
          #pragma unroll
          for (int kx = 0; kx < 7; kx++)
            #pragma unroll
            for (int j = 0; j < 4; j++)
              acc[oc][j] += iv[2*j+kx]*wk[kx];
        }
      }
      #pragma unroll
      for (int oc = 0; oc < 4; oc++)
        #pragma unroll
        for (int j = 0; j < 4; j++)
          conv_s[(oc*14 + r)*112 + c0 + j] = fmaxf(acc[oc][j], 0.f);
    }
    __syncthreads();
    // vertical max pass (values >= 0, so 0-init)
    for (int t = threadIdx.x; t < 4*PR*107; t += 256){
      int c = t % 107; int t2 = t / 107; int pr = t2 % PR; int oc = t2 / PR;
      int py = p0 + pr;
      float m = 0.f;
      for (int dy = 0; dy < 7; dy++){
        int rr = py-1+dy;
        if (rr < 0 || rr > 106) continue;
        m = fmaxf(m, conv_s[(oc*14 + (rr - cr0))*112 + c]);
      }
      vtmp_s[(oc*8+pr)*108 + c] = m;
    }
    __syncthreads();
    // horizontal max pass + NHWC write
    for (int t = threadIdx.x; t < 4*PR*103; t += 256){
      int pc = t % 103; int t2 = t / 103; int pr = t2 % PR; int oc = t2 / PR;
      int py = p0 + pr;
      const float* vp = &vtmp_s[(oc*8+pr)*108];
      float m = 0.f;
      for (int dx = 0; dx < 7; dx++){
        int cc = pc-1+dx;
        if (cc < 0 || cc > 106) continue;
        m = fmaxf(m, vp[cc]);
      }
      pool1[((n*103 + py)*103 + pc)*32 + grp*4 + oc] = __float2bfloat16(m);
    }
    __syncthreads();
  }
}

// ---------- K2: conv2 MFMA implicit GEMM. pool1 NHWC -> conv2out NHWC [CHUNK,49,49,64]
__global__ __launch_bounds__(256) void k2_conv2(
    const bf16* __restrict__ pool1,   // [CHUNK][103][103][32]
    const bf16* __restrict__ w2b,     // [49][64][32]
    bf16* __restrict__ conv2out)      // [CHUNK][49][49][64]
{
  __shared__ __align__(16) bf16 in_s[7*2*52*40];   // 58240 B
  const int n = blockIdx.y, pb = blockIdx.x;       // pb 0..9
  const int wv = threadIdx.x >> 6, lane = threadIdx.x & 63;
  const int li = lane & 15, lg = lane >> 4;
  const int p0 = pb*256;
  const int y0 = p0/49;

  int pyv[4], pxv[4], poff[4]; bool pmask[4];
  #pragma unroll
  for (int t = 0; t < 4; t++){
    int p = p0 + wv*64 + t*16 + li;
    pmask[t] = (p <= 2400);
    int pc = min(p, 2400);
    int yy = pc/49, xx = pc - yy*49;
    pyv[t] = yy; pxv[t] = xx;
    poff[t] = ((yy - y0)*2*52 + xx)*40;
  }
  floatx4 acc[4][4];
  #pragma unroll
  for (int a = 0; a < 4; a++)
    #pragma unroll
    for (int t = 0; t < 4; t++) acc[a][t] = (floatx4){0.f,0.f,0.f,0.f};

  for (int ky = 0; ky < 7; ky++){
    __syncthreads();
    for (int idx = threadIdx.x; idx < 7*103*4; idx += 256){
      int q = idx & 3; int t2 = idx >> 2; int c = t2 % 103; int r = t2/103;
      int gr = min(2*(y0+r)+ky, 102);
      const bf16* src = pool1 + (((long)n*103 + gr)*103 + c)*32 + q*8;
      bf16* dst = &in_s[((r*2 + (c&1))*52 + (c>>1))*40 + q*8];
      *(int4*)dst = *(const int4*)src;
    }
    __syncthreads();
    for (int kx = 0; kx < 7; kx++){
      short8 a[4];
      const bf16* wp = w2b + (ky*7+kx)*64*32;
      #pragma unroll
      for (int ot = 0; ot < 4; ot++)
        a[ot] = *(const short8*)(wp + (ot*16 + li)*32 + lg*8);
      int koff = ((kx&1)*52 + (kx>>1))*40 + lg*8;
      #pragma unroll
      for (int t = 0; t < 4; t++){
        short8 bfr = *(const short8*)(&in_s[poff[t] + koff]);
        #pragma unroll
        for (int ot = 0; ot < 4; ot++)
          acc[ot][t] = __builtin_amdgcn_mfma_f32_16x16x32_bf16(a[ot], bfr, acc[ot][t], 0, 0, 0);
      }
    }
  }
  #pragma unroll
  for (int t = 0; t < 4; t++){
    if (!pmask[t]) continue;
    bf16* dst = conv2out + (((long)n*49 + pyv[t])*49 + pxv[t])*64 + lg*4;
    #pragma unroll
    for (int ot = 0; ot < 4; ot++){
      union { bf16 h[4]; uint2 u; } pk;
      #pragma unroll
      for (int v = 0; v < 4; v++)
        pk.h[v] = __float2bfloat16(fmaxf(acc[ot][t][v], 0.f));
      *(uint2*)(dst + ot*16) = pk.u;
    }
  }
}

// ---------- K3a: horizontal 7-max: conv2out [CHUNK,49,49,64] -> tmp [CHUNK,49,45,64]
__global__ __launch_bounds__(256) void k3a_hmax(
    const bf16* __restrict__ cin, bf16* __restrict__ tmp)
{
  int idx = blockIdx.x*256 + threadIdx.x;   // CHUNK*49*45*8 = 1,128,960
  int cg = idx & 7; int t = idx >> 3; int x = t % 45; int t2 = t / 45;
  int y = t2 % 49; int n = t2 / 49;
  const int4* row = (const int4*)(cin + ((long)(n*49 + y)*49)*64) + cg;
  U8 m; m.v = make_int4(0,0,0,0);
  int lo = max(x-1, 0), hi = min(x+5, 48);
  for (int cx = lo; cx <= hi; cx++){ U8 v; v.v = row[cx*8]; umax8(m, v); }
  *((int4*)(tmp + ((long)(n*49 + y)*45 + x)*64) + cg) = m.v;
}

// ---------- K3b: vertical 7-max: tmp -> pool2 [256,45,45,64] at n_base
__global__ __launch_bounds__(256) void k3b_vmax(
    const bf16* __restrict__ tmp, bf16* __restrict__ pout, int n_base)
{
  int idx = blockIdx.x*256 + threadIdx.x;   // CHUNK*45*45*8 = 1,036,800
  int cg = idx & 7; int t = idx >> 3; int x = t % 45; int t2 = t / 45;
  int y = t2 % 45; int n = t2 / 45;
  U8 m; m.v = make_int4(0,0,0,0);
  int lo = max(y-1, 0), hi = min(y+5, 48);
  for (int cy = lo; cy <= hi; cy++){
    U8 v; v.v = *((const int4*)(tmp + ((long)(n*49 + cy)*45 + x)*64) + cg);
    umax8(m, v);
  }
  *((int4*)(pout + (long)(n_base+n)*129600 + (y*45 + x)*64) + cg) = m.v;
}

// ---------- K4: conv3 MFMA implicit GEMM. pool2 NHWC -> conv3out NHWC [256,20,20,64]
__global__ __launch_bounds__(256) void k4_conv3(
    const bf16* __restrict__ pool2,
    const bf16* __restrict__ w3b,     // [ky][kc][kx][64][32]
    bf16* __restrict__ conv3out)
{
  __shared__ __align__(16) bf16 in_s[10*2*24*40];  // 38400 B
  const int n = blockIdx.y, pb = blockIdx.x;       // pb 0..1
  const int wv = threadIdx.x >> 6, lane = threadIdx.x & 63;
  const int li = lane & 15, lg = lane >> 4;
  const int y0 = pb*10;

  int pyv[4], pxv[4], poff[4]; bool pmask[4];
  #pragma unroll
  for (int t = 0; t < 4; t++){
    int pl = wv*64 + t*16 + li;
    pmask[t] = (pl < 200);
    int p = pb*200 + min(pl, 199);
    int yy = p/20, xx = p - yy*20;
    pyv[t] = yy; pxv[t] = xx;
    poff[t] = ((yy - y0)*2*24 + xx)*40;
  }
  floatx4 acc[4][4];
  #pragma unroll
  for (int a = 0; a < 4; a++)
    #pragma unroll
    for (int t = 0; t < 4; t++) acc[a][t] = (floatx4){0.f,0.f,0.f,0.f};

  for (int ky = 0; ky < 7; ky++){
    for (int kc = 0; kc < 2; kc++){
      __syncthreads();
      for (int idx = threadIdx.x; idx < 10*45*4; idx += 256){
        int q = idx & 3; int t2 = idx >> 2; int c = t2 % 45; int r = t2/45;
        int gr = 2*(y0+r)+ky;
        const bf16* src = pool2 + (((long)n*45 + gr)*45 + c)*64 + kc*32 + q*8;
        bf16* dst = &in_s[((r*2 + (c&1))*24 + (c>>1))*40 + q*8];
        *(int4*)dst = *(const int4*)src;
      }
      __syncthreads();
      for (int kx = 0; kx < 7; kx++){
        short8 a[4];
        const bf16* wp = w3b + ((ky*2+kc)*7 + kx)*64*32;
        #pragma unroll
        for (int ot = 0; ot < 4; ot++)
          a[ot] = *(const short8*)(wp + (ot*16 + li)*32 + lg*8);
        int koff = ((kx&1)*24 + (kx>>1))*40 + lg*8;
        #pragma unroll
        for (int t = 0; t < 4; t++){
          short8 bfr = *(const short8*)(&in_s[poff[t] + koff]);
          #pragma unroll
          for (int ot = 0; ot < 4; ot++)
            acc[ot][t] = __builtin_amdgcn_mfma_f32_16x16x32_bf16(a[ot], bfr, acc[ot][t], 0, 0, 0);
        }
      }
    }
  }
  #pragma unroll
  for (int t = 0; t < 4; t++){
    if (!pmask[t]) continue;
    bf16* dst = conv3out + (((long)n*20 + pyv[t])*20 + pxv[t])*64 + lg*4;
    #pragma unroll
    for (int ot = 0; ot < 4; ot++){
      union { bf16 h[4]; uint2 u; } pk;
      #pragma unroll
      for (int v = 0; v < 4; v++)
        pk.h[v] = __float2bfloat16(fmaxf(acc[ot][t][v], 0.f));
      *(uint2*)(dst + ot*16) = pk.u;
    }
  }
}

// ---------- K5: in-LDS separable pool3. conv3out [256,20,20,64] -> feat [256,16384]
// feat flat order = (c, p1, p2) per patch. One block per patch.
__global__ __launch_bounds__(256) void k5_pool3(
    const bf16* __restrict__ cin, bf16* __restrict__ feat)
{
  __shared__ int4 in_p[3200];   // [y(20)][x(20)][cg(8)] = 51200 B
  __shared__ int4 ht[2560];     // [y(20)][x'(16)][cg(8)] = 40960 B
  const int n = blockIdx.x;
  const int4* src = (const int4*)(cin + (long)n*25600);
  for (int i = threadIdx.x; i < 3200; i += 256) in_p[i] = src[i];
  __syncthreads();
  // horizontal pass
  for (int i = threadIdx.x; i < 2560; i += 256){
    int cg = i & 7; int t = i >> 3; int x = t & 15; int y = t >> 4;
    U8 m; m.v = make_int4(0,0,0,0);
    int lo = max(x-1, 0), hi = min(x+5, 19);
    for (int cx = lo; cx <= hi; cx++){ U8 v; v.v = in_p[(y*20+cx)*8 + cg]; umax8(m, v); }
    ht[(y*16+x)*8 + cg] = m.v;
  }
  __syncthreads();
  // vertical pass + permuted write
  unsigned short* dst = (unsigned short*)(feat + (long)n*16384);
  for (int i = threadIdx.x; i < 2048; i += 256){
    int px = i & 15; int py = (i >> 4) & 15; int cg = i >> 8;
    U8 m; m.v = make_int4(0,0,0,0);
    int lo = max(py-1, 0), hi = min(py+5, 19);
    for (int cy = lo; cy <= hi; cy++){ U8 v; v.v = ht[(cy*16+px)*8 + cg]; umax8(m, v); }
    #pragma unroll
    for (int j = 0; j < 8; j++)
      dst[(cg*8+j)*256 + py*16 + px] = m.s[j];
  }
}

// ---------- K6a: init x[272,512]
__global__ __launch_bounds__(256) void k6_init_x(
    const float* __restrict__ cls, const float* __restrict__ pos,
    const float* __restrict__ flat_b, float* __restrict__ x)
{
  int idx = blockIdx.x*256 + threadIdx.x;
  int d = idx & 511; int row = idx >> 9;
  int tt = row % 17;
  x[idx] = (tt == 0) ? (cls[d] + pos[d]) : (flat_b[d] + pos[tt*512 + d]);
}

// ---------- K6b: feat @ flat_w -> atomicAdd into x
__global__ __launch_bounds__(256) void k6_flat_gemm(
    const bf16* __restrict__ feat, const float* __restrict__ W,
    float* __restrict__ x)
{
  __shared__ float A_s[32][33];
  __shared__ __align__(16) float W_s[32][68];
  const int m0 = blockIdx.x*32, n0 = blockIdx.y*64, ks = blockIdx.z;
  const int r = threadIdx.x>>4, c0 = (threadIdx.x&15)*4;
  float acc0[4] = {}, acc1[4] = {};
  for (int kt = 0; kt < 64; kt++){
    int k0 = ks*2048 + kt*32;
    __syncthreads();
    for (int i = 0; i < 4; i++){ int id = threadIdx.x + i*256; int rr = id>>5, kk = id&31;
      A_s[rr][kk] = __bfloat162float(feat[(long)(m0+rr)*16384 + k0+kk]); }
    for (int i = 0; i < 8; i++){ int id = threadIdx.x + i*256; int kk = id>>6, c = id&63;
      W_s[kk][c] = W[(long)(k0+kk)*512 + n0+c]; }
    __syncthreads();
    #pragma unroll
    for (int kk = 0; kk < 32; kk++){
      float a0 = A_s[r][kk], a1 = A_s[r+16][kk];
      float4 w4 = *(const float4*)&W_s[kk][c0];
      acc0[0]+=a0*w4.x; acc0[1]+=a0*w4.y; acc0[2]+=a0*w4.z; acc0[3]+=a0*w4.w;
      acc1[0]+=a1*w4.x; acc1[1]+=a1*w4.y; acc1[2]+=a1*w4.z; acc1[3]+=a1*w4.w;
    }
  }
  int ma = m0+r, mb = m0+r+16;
  int rowa = (ma>>4)*17 + 1 + (ma&15);
  int rowb = (mb>>4)*17 + 1 + (mb&15);
  for (int j = 0; j < 4; j++){
    atomicAdd(&x[rowa*512 + n0+c0+j], acc0[j]);
    atomicAdd(&x[rowb*512 + n0+c0+j], acc1[j]);
  }
}

// ---------- LayerNorm over 512
__global__ __launch_bounds__(256) void ln_kernel(
    const float* __restrict__ in, const float* __restrict__ g,
    const float* __restrict__ b, float* __restrict__ out,
    int in_stride, int out_stride)
{
  int row = blockIdx.x;
  const float* p = in + (long)row*in_stride;
  float v0 = p[threadIdx.x], v1 = p[threadIdx.x+256];
  __shared__ float red[4]; __shared__ float stat;
  float s = v0+v1;
  #pragma unroll
  for (int o = 32; o >= 1; o >>= 1) s += __shfl_down(s, o);
  int lane = threadIdx.x & 63, wv = threadIdx.x >> 6;
  if (lane == 0) red[wv] = s;
  __syncthreads();
  if (threadIdx.x == 0) stat = (red[0]+red[1]+red[2]+red[3])*(1.0f/512.0f);
  __syncthreads();
  float m = stat;
  float d0 = v0-m, d1 = v1-m;
  float q = d0*d0 + d1*d1;
  #pragma unroll
  for (int o = 32; o >= 1; o >>= 1) q += __shfl_down(q, o);
  __syncthreads();
  if (lane == 0) red[wv] = q;
  __syncthreads();
  if (threadIdx.x == 0) stat = rsqrtf((red[0]+red[1]+red[2]+red[3])*(1.0f/512.0f) + 1e-5f);
  __syncthreads();
  float rstd = stat;
  out[(long)row*out_stride + threadIdx.x]     = d0*rstd*g[threadIdx.x]     + b[threadIdx.x];
  out[(long)row*out_stride + threadIdx.x+256] = d1*rstd*g[threadIdx.x+256] + b[threadIdx.x+256];
}

// ---------- Generic small GEMM: out = [res +] act(A@W + bias)
__global__ __launch_bounds__(256) void gemm_rows(
    const float* __restrict__ A, const float* __restrict__ W,
    const float* __restrict__ bias, const float* __restrict__ res,
    float* __restrict__ out, int M, int N, int K, int dogelu)
{
  __shared__ float A_s[16][33];
  __shared__ __align__(16) float W_s[32][68];
  const int m0 = blockIdx.x*16, n0 = blockIdx.y*64;
  const int r = threadIdx.x>>4, c0 = (threadIdx.x&15)*4;
  float acc[4] = {};
  for (int k0 = 0; k0 < K; k0 += 32){
    __syncthreads();
    for (int i = 0; i < 2; i++){ int id = threadIdx.x + i*256; int rr = id>>5, kk = id&31;
      A_s[rr][kk] = (m0+rr < M) ? A[(long)(m0+rr)*K + k0+kk] : 0.f; }
    for (int i = 0; i < 8; i++){ int id = threadIdx.x + i*256; int kk = id>>6, c = id&63;
      W_s[kk][c] = (n0+c < N) ? W[(long)(k0+kk)*N + n0+c] : 0.f; }
    __syncthreads();
    #pragma unroll
    for (int kk = 0; kk < 32; kk++){
      float a = A_s[r][kk];
      float4 w4 = *(const float4*)&W_s[kk][c0];
      acc[0]+=a*w4.x; acc[1]+=a*w4.y; acc[2]+=a*w4.z; acc[3]+=a*w4.w;
    }
  }
  if (m0+r < M){
    int row = m0+r;
    for (int j = 0; j < 4; j++){
      int c = n0+c0+j;
      if (c < N){
        float v = acc[j];
        if (bias) v += bias[c];
        if (dogelu) v = 0.5f*v*(1.0f + erff(v*0.70710678118654752f));
        if (res) v += res[(long)row*N + c];
        out[(long)row*N + c] = v;
      }
    }
  }
}

// ---------- Attention: one block per (b,h). N=17, DH=64.
__global__ __launch_bounds__(128) void attn_kernel(
    const float* __restrict__ qkv, float* __restrict__ obuf)
{
  const int b = blockIdx.x >> 3, h = blockIdx.x & 7;
  __shared__ float q_s[17][65], k_s[17][65], v_s[17][65], s_s[17][18];
  for (int idx = threadIdx.x; idx < 17*64; idx += 128){
    int i = idx>>6, d = idx&63;
    const float* base = qkv + (long)(b*17+i)*1536 + h*64 + d;
    q_s[i][d] = base[0]; k_s[i][d] = base[512]; v_s[i][d] = base[1024];
  }
  __syncthreads();
  for (int idx = threadIdx.x; idx < 289; idx += 128){
    int i = idx/17, j = idx - i*17;
    float s = 0.f;
    for (int d = 0; d < 64; d++) s += q_s[i][d]*k_s[j][d];
    s_s[i][j] = s*0.125f;
  }
  __syncthreads();
  if (threadIdx.x < 17){
    int i = threadIdx.x;
    float m = -1e30f;
    for (int j = 0; j < 17; j++) m = fmaxf(m, s_s[i][j]);
    float sum = 0.f;
    for (int j = 0; j < 17; j++){ float e = expf(s_s[i][j]-m); s_s[i][j] = e; sum += e; }
    float inv = 1.0f/sum;
    for (int j = 0; j < 17; j++) s_s[i][j] *= inv;
  }
  __syncthreads();
  for (int idx = threadIdx.x; idx < 17*64; idx += 128){
    int i = idx>>6, d = idx&63;
    float o = 0.f;
    for (int j = 0; j < 17; j++) o += s_s[i][j]*v_s[j][d];
    obuf[(long)(b*17+i)*512 + h*64 + d] = o;
  }
}

// ============================================================================
extern "C" void kernel_launch(void* const* d_in, const int* in_sizes, int n_in,
                              void* d_out, int out_size, void* d_ws, size_t ws_size,
                              hipStream_t stream) {
  const float* img      = (const float*)d_in[0];
  const float* conv1_w  = (const float*)d_in[1];
  const float* conv2_w  = (const float*)d_in[2];
  const float* conv3_w  = (const float*)d_in[3];
  const float* flat_w   = (const float*)d_in[4];
  const float* flat_b   = (const float*)d_in[5];
  const float* cls_tok  = (const float*)d_in[6];
  const float* pos_emb  = (const float*)d_in[7];
  const float* ln1_g    = (const float*)d_in[8];
  const float* ln1_b    = (const float*)d_in[9];
  const float* qkv_w    = (const float*)d_in[10];
  const float* out_w    = (const float*)d_in[11];
  const float* out_b    = (const float*)d_in[12];
  const float* ln2_g    = (const float*)d_in[13];
  const float* ln2_b    = (const float*)d_in[14];
  const float* ff1_w    = (const float*)d_in[15];
  const float* ff1_b    = (const float*)d_in[16];
  const float* ff2_w    = (const float*)d_in[17];
  const float* ff2_b    = (const float*)d_in[18];
  const float* hln_g    = (const float*)d_in[19];
  const float* hln_b    = (const float*)d_in[20];
  const float* head_w   = (const float*)d_in[21];
  const float* head_b   = (const float*)d_in[22];

  char* ws = (char*)d_ws;
  size_t off = 0;
  auto alloc = [&](size_t bytes) -> void* {
    void* p = ws + off; off += (bytes + 255) & ~(size_t)255; return p;
  };
  bf16* pool1    = (bf16*)alloc((size_t)CHUNK*103*103*32*2);  // 43.5 MB (chunk, NHWC)
  bf16* conv2out = (bf16*)alloc((size_t)CHUNK*49*49*64*2);    // 19.7 MB (chunk, NHWC)
  bf16* pool2    = (bf16*)alloc((size_t)256*45*45*64*2);      // 66.4 MB (full, NHWC)
  bf16* feat     = (bf16*)alloc((size_t)256*16384*2);         //  8.4 MB
  bf16* w2b      = (bf16*)alloc((size_t)49*64*32*2);
  bf16* w3b      = (bf16*)alloc((size_t)49*2*64*32*2);
  float* x       = (float*)alloc((size_t)139264*4);
  float* h       = (float*)alloc((size_t)139264*4);
  float* qkvb    = (float*)alloc((size_t)417792*4);
  float* obuf    = (float*)alloc((size_t)139264*4);
  float* ffbuf   = (float*)alloc((size_t)557056*4);
  float* hcls    = (float*)alloc((size_t)8192*4);
  // pool1 is dead during k3a/k3b (within chunk) and after the chunk loop:
  bf16* tmp3     = pool1;   // k3 horizontal-pass tmp: 18.1 MB <= 43.5 MB
  bf16* conv3out = pool1;   // k4 output: 13.1 MB <= 43.5 MB
  (void)ws_size; (void)in_sizes; (void)n_in; (void)out_size;

  prep_w2<<<392, 256, 0, stream>>>(conv2_w, w2b);
  prep_w3<<<784, 256, 0, stream>>>(conv3_w, w3b);

  // CNN stem: chunks for k1-k3 (pool2 written full), then k4/k5 over all patches
  for (int cb = 0; cb < 256; cb += CHUNK){
    k1_conv1_pool<<<dim3(13,CHUNK), 256, 0, stream>>>(img, conv1_w, pool1, cb);
    k2_conv2     <<<dim3(10,CHUNK), 256, 0, stream>>>(pool1, w2b, conv2out);
    k3a_hmax     <<<(CHUNK*49*45*8)/256, 256, 0, stream>>>(conv2out, tmp3);
    k3b_vmax     <<<(CHUNK*45*45*8)/256, 256, 0, stream>>>(tmp3, pool2, cb);
  }
  k4_conv3<<<dim3(2,256), 256, 0, stream>>>(pool2, w3b, conv3out);
  k5_pool3<<<256, 256, 0, stream>>>(conv3out, feat);

  // Flatten projection + token assembly
  k6_init_x    <<<544,          256, 0, stream>>>(cls_tok, pos_emb, flat_b, x);
  k6_flat_gemm <<<dim3(8,8,8),  256, 0, stream>>>(feat, flat_w, x);

  // Transformer layers
  for (int l = 0; l < 6; l++){
    ln_kernel<<<272, 256, 0, stream>>>(x, ln1_g + l*512, ln1_b + l*512, h, 512, 512);
    gemm_rows<<<dim3(17,24), 256, 0, stream>>>(h, qkv_w + (size_t)l*786432,
                                               nullptr, nullptr, qkvb, 272, 1536, 512, 0);
    attn_kernel<<<128, 128, 0, stream>>>(qkvb, obuf);
    gemm_rows<<<dim3(17,8), 256, 0, stream>>>(obuf, out_w + (size_t)l*262144,
                                              out_b + l*512, x, x, 272, 512, 512, 0);
    ln_kernel<<<272, 256, 0, stream>>>(x, ln2_g + l*512, ln2_b + l*512, h, 512, 512);
    gemm_rows<<<dim3(17,32), 256, 0, stream>>>(h, ff1_w + (size_t)l*1048576,
                                               ff1_b + l*2048, nullptr, ffbuf, 272, 2048, 512, 1);
    gemm_rows<<<dim3(17,8), 256, 0, stream>>>(ffbuf, ff2_w + (size_t)l*1048576,
                                              ff2_b + l*512, x, x, 272, 512, 2048, 0);
  }

  // Head
  ln_kernel<<<16, 256, 0, stream>>>(x, hln_g, hln_b, hcls, 17*512, 512);
  gemm_rows<<<dim3(1,16), 256, 0, stream>>>(hcls, head_w, head_b, nullptr,
                                            (float*)d_out, 16, 1000, 512, 0);
}

// Round 5
// 3915.899 us; speedup vs baseline: 2.5541x; 1.0851x over previous
//
#include <hip/hip_runtime.h>
#include <hip/hip_bf16.h>

// ============================================================================
// HybridViT forward. Round 5: k1 rewrite.
//  - pool1 blocked layout [n][grp8][103][103][4ch] -> coalesced uint2 pool
//    writes (round-4 counter: WRITE_SIZE 287MB vs 46MB data = 6.3x write amp
//    from 2B stores at 64B stride).
//  - 8 strips x 13 pooled rows (conv redundancy 1.7x -> 1.43x); conv_s/vtmp
//    in bf16/u16 bits (max commutes with monotone rounding -> bit-identical).
//  - float4 img staging, uint2 conv_s writes (kills stride-4 LDS conflicts).
//  - k2 stager adapted to blocked layout (2x uint2 per 8-channel granule).
// ============================================================================

typedef __hip_bfloat16 bf16;
typedef __attribute__((ext_vector_type(8))) short short8;
typedef __attribute__((ext_vector_type(4))) float floatx4;

#define CHUNK 64

union U8 { int4 v; unsigned short s[8]; };
__device__ inline void umax8(U8& a, const U8& b){
  #pragma unroll
  for (int j = 0; j < 8; j++) a.s[j] = (a.s[j] > b.s[j]) ? a.s[j] : b.s[j];
}

// ---------- weight prep: conv2_w fp32 [64][32][7][7] -> bf16 [ky*7+kx][64][32]
__global__ __launch_bounds__(256) void prep_w2(const float* __restrict__ w,
                                               bf16* __restrict__ w2b)
{
  int idx = blockIdx.x*256 + threadIdx.x;     // 49*64*32 = 100352
  if (idx >= 49*64*32) return;
  int ic = idx & 31; int t = idx >> 5; int oc = t & 63; int kk = t >> 6;
  int ky = kk/7, kx = kk - ky*7;
  w2b[idx] = __float2bfloat16(w[((oc*32+ic)*7+ky)*7+kx]);
}

// ---------- weight prep: conv3_w fp32 [64][64][7][7] -> bf16 [ky][kc][kx][64][32]
__global__ __launch_bounds__(256) void prep_w3(const float* __restrict__ w,
                                               bf16* __restrict__ w3b)
{
  int idx = blockIdx.x*256 + threadIdx.x;     // 49*2*64*32 = 200704
  if (idx >= 49*2*64*32) return;
  int ic_l = idx & 31; int t = idx >> 5; int oc = t & 63; int t2 = t >> 6;
  int kx = t2 % 7; int t3 = t2 / 7; int kc = t3 & 1; int ky = t3 >> 1;
  w3b[idx] = __float2bfloat16(w[((oc*64 + kc*32 + ic_l)*7+ky)*7+kx]);
}

// ---------- K1: patchify + conv1(1->32,7x7,s2) + ReLU + separable pool
//   -> pool1 blocked [CHUNK][8grp][103][103][4ch] bf16
// 8 strips of 13 pooled rows. conv_s/vtmp hold bf16 bits (u16 compares).
__global__ __launch_bounds__(256) void k1_conv1_pool(
    const float* __restrict__ img, const float* __restrict__ w,
    bf16* __restrict__ pool1, int n_base)
{
  __shared__ __align__(16) float in_s[43*224];              // 38528 B
  __shared__ __align__(16) unsigned short conv_s[4*19*112]; // 17024 B
  __shared__ __align__(16) float w_s[32*56];                //  7168 B
  __shared__ __align__(16) unsigned short vtmp_s[13*112*4]; // 11648 B [pr][c][oc4]
  const int strip = blockIdx.x;        // 0..7
  const int n = blockIdx.y;            // local patch
  const int ng = n_base + n;
  const int p0 = strip*13;
  const int PR = min(13, 103-p0);      // 13 (last strip 12)
  const int cr0 = max(p0-1, 0);
  const int cr1 = min(p0+PR+4, 106);
  const int CR = cr1-cr0+1;            // <=19
  const int ir0 = 2*cr0;
  const int IR = 2*CR+5;               // <=43
  const int b = ng>>4, gh = (ng>>2)&3, gw = ng&3;
  const float* ibase = img + b*774400 + (gh*220)*880 + gw*220;

  // stage input rows, float4
  for (int idx = threadIdx.x; idx < IR*56; idx += 256){
    int r = idx/56, cq = idx - r*56; int c = cq*4;
    float4 v = (c < 220) ? *(const float4*)(ibase + (ir0+r)*880 + c)
                         : make_float4(0.f,0.f,0.f,0.f);
    *(float4*)&in_s[r*224 + c] = v;
  }
  for (int idx = threadIdx.x; idx < 32*56; idx += 256){
    int oc = idx/56, k = idx - oc*56; int ky = k>>3, kx = k&7;
    w_s[idx] = (kx < 7 && ky < 7) ? w[oc*49 + ky*7 + kx] : 0.f;
  }
  __syncthreads();

  for (int grp = 0; grp < 8; grp++){   // 8 groups of 4 output channels
    // conv + ReLU -> conv_s (bf16 bits)
    for (int t = threadIdx.x; t < CR*27; t += 256){
      int r = t/27, g = t - r*27; int c0 = g*4;
      float acc[4][4] = {};
      for (int ky = 0; ky < 7; ky++){
        const float* ip = &in_s[(2*r+ky)*224 + 2*c0];
        float iv[13];
        *(float4*)&iv[0] = *(const float4*)ip;
        *(float4*)&iv[4] = *(const float4*)(ip+4);
        *(float4*)&iv[8] = *(const float4*)(ip+8);
        iv[12] = ip[12];
        #pragma unroll
        for (int oc = 0; oc < 4; oc++){
          const float* wp = &w_s[(grp*4+oc)*56 + ky*8];
          float4 wa = *(const float4*)wp;
          float4 wb = *(const float4*)(wp+4);
          float wk[7] = {wa.x,wa.y,wa.z,wa.w,wb.x,wb.y,wb.z};
          #pragma unroll
          for (int kx = 0; kx < 7; kx++)
            #pragma unroll
            for (int j = 0; j < 4; j++)
              acc[oc][j] += iv[2*j+kx]*wk[kx];
        }
      }
      #pragma unroll
      for (int oc = 0; oc < 4; oc++){
        union { unsigned short s[4]; uint2 u; } pk;
        #pragma unroll
        for (int j = 0; j < 4; j++){
          bf16 hv = __float2bfloat16(fmaxf(acc[oc][j], 0.f));
          pk.s[j] = *(unsigned short*)&hv;
        }
        *(uint2*)&conv_s[(oc*19 + r)*112 + c0] = pk.u;
      }
    }
    __syncthreads();
    // vertical 7-max: conv_s -> vtmp [pr][c][oc4]
    for (int t = threadIdx.x; t < PR*107*4; t += 256){
      int oc = t & 3; int t2 = t >> 2; int c = t2 % 107; int pr = t2/107;
      int py = p0 + pr;
      unsigned short m = 0;
      for (int dy = 0; dy < 7; dy++){
        int rr = py-1+dy;
        if (rr < 0 || rr > 106) continue;
        unsigned short v = conv_s[(oc*19 + (rr - cr0))*112 + c];
        m = (v > m) ? v : m;
      }
      vtmp_s[(pr*112 + c)*4 + oc] = m;
    }
    __syncthreads();
    // horizontal 7-max + coalesced blocked write (uint2 = 4ch)
    for (int t = threadIdx.x; t < PR*103; t += 256){
      int pc = t % 103; int pr = t/103;
      int py = p0 + pr;
      unsigned short m0=0, m1=0, m2=0, m3=0;
      int lo = max(pc-1, 0), hi = min(pc+5, 106);
      for (int cc = lo; cc <= hi; cc++){
        union { uint2 u; unsigned short s[4]; } v;
        v.u = *(const uint2*)&vtmp_s[(pr*112 + cc)*4];
        m0 = (v.s[0] > m0) ? v.s[0] : m0;
        m1 = (v.s[1] > m1) ? v.s[1] : m1;
        m2 = (v.s[2] > m2) ? v.s[2] : m2;
        m3 = (v.s[3] > m3) ? v.s[3] : m3;
      }
      union { unsigned short s[4]; uint2 u; } pk;
      pk.s[0]=m0; pk.s[1]=m1; pk.s[2]=m2; pk.s[3]=m3;
      *(uint2*)((unsigned short*)pool1 +
                ((size_t)(n*8 + grp)*10609 + py*103 + pc)*4) = pk.u;
    }
    __syncthreads();
  }
}

// ---------- K2: conv2 MFMA implicit GEMM. pool1 blocked -> conv2out NHWC [CHUNK,49,49,64]
__global__ __launch_bounds__(256) void k2_conv2(
    const bf16* __restrict__ pool1,   // [CHUNK][8][103][103][4]
    const bf16* __restrict__ w2b,     // [49][64][32]
    bf16* __restrict__ conv2out)      // [CHUNK][49][49][64]
{
  __shared__ __align__(16) bf16 in_s[7*2*52*40];   // 58240 B
  const int n = blockIdx.y, pb = blockIdx.x;       // pb 0..9
  const int wv = threadIdx.x >> 6, lane = threadIdx.x & 63;
  const int li = lane & 15, lg = lane >> 4;
  const int p0 = pb*256;
  const int y0 = p0/49;

  int pyv[4], pxv[4], poff[4]; bool pmask[4];
  #pragma unroll
  for (int t = 0; t < 4; t++){
    int p = p0 + wv*64 + t*16 + li;
    pmask[t] = (p <= 2400);
    int pc = min(p, 2400);
    int yy = pc/49, xx = pc - yy*49;
    pyv[t] = yy; pxv[t] = xx;
    poff[t] = ((yy - y0)*2*52 + xx)*40;
  }
  floatx4 acc[4][4];
  #pragma unroll
  for (int a = 0; a < 4; a++)
    #pragma unroll
    for (int t = 0; t < 4; t++) acc[a][t] = (floatx4){0.f,0.f,0.f,0.f};

  const unsigned short* pbase = (const unsigned short*)pool1;
  for (int ky = 0; ky < 7; ky++){
    __syncthreads();
    for (int idx = threadIdx.x; idx < 7*103*4; idx += 256){
      int q = idx & 3; int t2 = idx >> 2; int c = t2 % 103; int r = t2/103;
      int gr = min(2*(y0+r)+ky, 102);
      size_t pix = (size_t)gr*103 + c;
      uint2 lov = *(const uint2*)(pbase + (((size_t)n*8 + 2*q  )*10609 + pix)*4);
      uint2 hiv = *(const uint2*)(pbase + (((size_t)n*8 + 2*q+1)*10609 + pix)*4);
      int4 vv; vv.x = (int)lov.x; vv.y = (int)lov.y; vv.z = (int)hiv.x; vv.w = (int)hiv.y;
      *(int4*)&in_s[((r*2 + (c&1))*52 + (c>>1))*40 + q*8] = vv;
    }
    __syncthreads();
    for (int kx = 0; kx < 7; kx++){
      short8 a[4];
      const bf16* wp = w2b + (ky*7+kx)*64*32;
      #pragma unroll
      for (int ot = 0; ot < 4; ot++)
        a[ot] = *(const short8*)(wp + (ot*16 + li)*32 + lg*8);
      int koff = ((kx&1)*52 + (kx>>1))*40 + lg*8;
      #pragma unroll
      for (int t = 0; t < 4; t++){
        short8 bfr = *(const short8*)(&in_s[poff[t] + koff]);
        #pragma unroll
        for (int ot = 0; ot < 4; ot++)
          acc[ot][t] = __builtin_amdgcn_mfma_f32_16x16x32_bf16(a[ot], bfr, acc[ot][t], 0, 0, 0);
      }
    }
  }
  #pragma unroll
  for (int t = 0; t < 4; t++){
    if (!pmask[t]) continue;
    bf16* dst = conv2out + (((long)n*49 + pyv[t])*49 + pxv[t])*64 + lg*4;
    #pragma unroll
    for (int ot = 0; ot < 4; ot++){
      union { bf16 h[4]; uint2 u; } pk;
      #pragma unroll
      for (int v = 0; v < 4; v++)
        pk.h[v] = __float2bfloat16(fmaxf(acc[ot][t][v], 0.f));
      *(uint2*)(dst + ot*16) = pk.u;
    }
  }
}

// ---------- K3a: horizontal 7-max: conv2out [CHUNK,49,49,64] -> tmp [CHUNK,49,45,64]
__global__ __launch_bounds__(256) void k3a_hmax(
    const bf16* __restrict__ cin, bf16* __restrict__ tmp)
{
  int idx = blockIdx.x*256 + threadIdx.x;   // CHUNK*49*45*8
  int cg = idx & 7; int t = idx >> 3; int x = t % 45; int t2 = t / 45;
  int y = t2 % 49; int n = t2 / 49;
  const int4* row = (const int4*)(cin + ((long)(n*49 + y)*49)*64) + cg;
  U8 m; m.v = make_int4(0,0,0,0);
  int lo = max(x-1, 0), hi = min(x+5, 48);
  for (int cx = lo; cx <= hi; cx++){ U8 v; v.v = row[cx*8]; umax8(m, v); }
  *((int4*)(tmp + ((long)(n*49 + y)*45 + x)*64) + cg) = m.v;
}

// ---------- K3b: vertical 7-max: tmp -> pool2 [256,45,45,64] at n_base
__global__ __launch_bounds__(256) void k3b_vmax(
    const bf16* __restrict__ tmp, bf16* __restrict__ pout, int n_base)
{
  int idx = blockIdx.x*256 + threadIdx.x;   // CHUNK*45*45*8
  int cg = idx & 7; int t = idx >> 3; int x = t % 45; int t2 = t / 45;
  int y = t2 % 45; int n = t2 / 45;
  U8 m; m.v = make_int4(0,0,0,0);
  int lo = max(y-1, 0), hi = min(y+5, 48);
  for (int cy = lo; cy <= hi; cy++){
    U8 v; v.v = *((const int4*)(tmp + ((long)(n*49 + cy)*45 + x)*64) + cg);
    umax8(m, v);
  }
  *((int4*)(pout + (long)(n_base+n)*129600 + (y*45 + x)*64) + cg) = m.v;
}

// ---------- K4: conv3 MFMA implicit GEMM. pool2 NHWC -> conv3out NHWC [256,20,20,64]
__global__ __launch_bounds__(256) void k4_conv3(
    const bf16* __restrict__ pool2,
    const bf16* __restrict__ w3b,     // [ky][kc][kx][64][32]
    bf16* __restrict__ conv3out)
{
  __shared__ __align__(16) bf16 in_s[10*2*24*40];  // 38400 B
  const int n = blockIdx.y, pb = blockIdx.x;       // pb 0..1
  const int wv = threadIdx.x >> 6, lane = threadIdx.x & 63;
  const int li = lane & 15, lg = lane >> 4;
  const int y0 = pb*10;

  int pyv[4], pxv[4], poff[4]; bool pmask[4];
  #pragma unroll
  for (int t = 0; t < 4; t++){
    int pl = wv*64 + t*16 + li;
    pmask[t] = (pl < 200);
    int p = pb*200 + min(pl, 199);
    int yy = p/20, xx = p - yy*20;
    pyv[t] = yy; pxv[t] = xx;
    poff[t] = ((yy - y0)*2*24 + xx)*40;
  }
  floatx4 acc[4][4];
  #pragma unroll
  for (int a = 0; a < 4; a++)
    #pragma unroll
    for (int t = 0; t < 4; t++) acc[a][t] = (floatx4){0.f,0.f,0.f,0.f};

  for (int ky = 0; ky < 7; ky++){
    for (int kc = 0; kc < 2; kc++){
      __syncthreads();
      for (int idx = threadIdx.x; idx < 10*45*4; idx += 256){
        int q = idx & 3; int t2 = idx >> 2; int c = t2 % 45; int r = t2/45;
        int gr = 2*(y0+r)+ky;
        const bf16* src = pool2 + (((long)n*45 + gr)*45 + c)*64 + kc*32 + q*8;
        bf16* dst = &in_s[((r*2 + (c&1))*24 + (c>>1))*40 + q*8];
        *(int4*)dst = *(const int4*)src;
      }
      __syncthreads();
      for (int kx = 0; kx < 7; kx++){
        short8 a[4];
        const bf16* wp = w3b + ((ky*2+kc)*7 + kx)*64*32;
        #pragma unroll
        for (int ot = 0; ot < 4; ot++)
          a[ot] = *(const short8*)(wp + (ot*16 + li)*32 + lg*8);
        int koff = ((kx&1)*24 + (kx>>1))*40 + lg*8;
        #pragma unroll
        for (int t = 0; t < 4; t++){
          short8 bfr = *(const short8*)(&in_s[poff[t] + koff]);
          #pragma unroll
          for (int ot = 0; ot < 4; ot++)
            acc[ot][t] = __builtin_amdgcn_mfma_f32_16x16x32_bf16(a[ot], bfr, acc[ot][t], 0, 0, 0);
        }
      }
    }
  }
  #pragma unroll
  for (int t = 0; t < 4; t++){
    if (!pmask[t]) continue;
    bf16* dst = conv3out + (((long)n*20 + pyv[t])*20 + pxv[t])*64 + lg*4;
    #pragma unroll
    for (int ot = 0; ot < 4; ot++){
      union { bf16 h[4]; uint2 u; } pk;
      #pragma unroll
      for (int v = 0; v < 4; v++)
        pk.h[v] = __float2bfloat16(fmaxf(acc[ot][t][v], 0.f));
      *(uint2*)(dst + ot*16) = pk.u;
    }
  }
}

// ---------- K5: in-LDS separable pool3. conv3out [256,20,20,64] -> feat [256,16384]
__global__ __launch_bounds__(256) void k5_pool3(
    const bf16* __restrict__ cin, bf16* __restrict__ feat)
{
  __shared__ int4 in_p[3200];   // [y20][x20][cg8] = 51200 B
  __shared__ int4 ht[2560];     // [y20][x'16][cg8] = 40960 B
  const int n = blockIdx.x;
  const int4* src = (const int4*)(cin + (long)n*25600);
  for (int i = threadIdx.x; i < 3200; i += 256) in_p[i] = src[i];
  __syncthreads();
  for (int i = threadIdx.x; i < 2560; i += 256){
    int cg = i & 7; int t = i >> 3; int x = t & 15; int y = t >> 4;
    U8 m; m.v = make_int4(0,0,0,0);
    int lo = max(x-1, 0), hi = min(x+5, 19);
    for (int cx = lo; cx <= hi; cx++){ U8 v; v.v = in_p[(y*20+cx)*8 + cg]; umax8(m, v); }
    ht[(y*16+x)*8 + cg] = m.v;
  }
  __syncthreads();
  unsigned short* dst = (unsigned short*)(feat + (long)n*16384);
  for (int i = threadIdx.x; i < 2048; i += 256){
    int px = i & 15; int py = (i >> 4) & 15; int cg = i >> 8;
    U8 m; m.v = make_int4(0,0,0,0);
    int lo = max(py-1, 0), hi = min(py+5, 19);
    for (int cy = lo; cy <= hi; cy++){ U8 v; v.v = ht[(cy*16+px)*8 + cg]; umax8(m, v); }
    #pragma unroll
    for (int j = 0; j < 8; j++)
      dst[(cg*8+j)*256 + py*16 + px] = m.s[j];
  }
}

// ---------- K6a: init x[272,512]
__global__ __launch_bounds__(256) void k6_init_x(
    const float* __restrict__ cls, const float* __restrict__ pos,
    const float* __restrict__ flat_b, float* __restrict__ x)
{
  int idx = blockIdx.x*256 + threadIdx.x;
  int d = idx & 511; int row = idx >> 9;
  int tt = row % 17;
  x[idx] = (tt == 0) ? (cls[d] + pos[d]) : (flat_b[d] + pos[tt*512 + d]);
}

// ---------- K6b: feat @ flat_w -> atomicAdd into x
__global__ __launch_bounds__(256) void k6_flat_gemm(
    const bf16* __restrict__ feat, const float* __restrict__ W,
    float* __restrict__ x)
{
  __shared__ float A_s[32][33];
  __shared__ __align__(16) float W_s[32][68];
  const int m0 = blockIdx.x*32, n0 = blockIdx.y*64, ks = blockIdx.z;
  const int r = threadIdx.x>>4, c0 = (threadIdx.x&15)*4;
  float acc0[4] = {}, acc1[4] = {};
  for (int kt = 0; kt < 64; kt++){
    int k0 = ks*2048 + kt*32;
    __syncthreads();
    for (int i = 0; i < 4; i++){ int id = threadIdx.x + i*256; int rr = id>>5, kk = id&31;
      A_s[rr][kk] = __bfloat162float(feat[(long)(m0+rr)*16384 + k0+kk]); }
    for (int i = 0; i < 8; i++){ int id = threadIdx.x + i*256; int kk = id>>6, c = id&63;
      W_s[kk][c] = W[(long)(k0+kk)*512 + n0+c]; }
    __syncthreads();
    #pragma unroll
    for (int kk = 0; kk < 32; kk++){
      float a0 = A_s[r][kk], a1 = A_s[r+16][kk];
      float4 w4 = *(const float4*)&W_s[kk][c0];
      acc0[0]+=a0*w4.x; acc0[1]+=a0*w4.y; acc0[2]+=a0*w4.z; acc0[3]+=a0*w4.w;
      acc1[0]+=a1*w4.x; acc1[1]+=a1*w4.y; acc1[2]+=a1*w4.z; acc1[3]+=a1*w4.w;
    }
  }
  int ma = m0+r, mb = m0+r+16;
  int rowa = (ma>>4)*17 + 1 + (ma&15);
  int rowb = (mb>>4)*17 + 1 + (mb&15);
  for (int j = 0; j < 4; j++){
    atomicAdd(&x[rowa*512 + n0+c0+j], acc0[j]);
    atomicAdd(&x[rowb*512 + n0+c0+j], acc1[j]);
  }
}

// ---------- LayerNorm over 512
__global__ __launch_bounds__(256) void ln_kernel(
    const float* __restrict__ in, const float* __restrict__ g,
    const float* __restrict__ b, float* __restrict__ out,
    int in_stride, int out_stride)
{
  int row = blockIdx.x;
  const float* p = in + (long)row*in_stride;
  float v0 = p[threadIdx.x], v1 = p[threadIdx.x+256];
  __shared__ float red[4]; __shared__ float stat;
  float s = v0+v1;
  #pragma unroll
  for (int o = 32; o >= 1; o >>= 1) s += __shfl_down(s, o);
  int lane = threadIdx.x & 63, wv = threadIdx.x >> 6;
  if (lane == 0) red[wv] = s;
  __syncthreads();
  if (threadIdx.x == 0) stat = (red[0]+red[1]+red[2]+red[3])*(1.0f/512.0f);
  __syncthreads();
  float m = stat;
  float d0 = v0-m, d1 = v1-m;
  float q = d0*d0 + d1*d1;
  #pragma unroll
  for (int o = 32; o >= 1; o >>= 1) q += __shfl_down(q, o);
  __syncthreads();
  if (lane == 0) red[wv] = q;
  __syncthreads();
  if (threadIdx.x == 0) stat = rsqrtf((red[0]+red[1]+red[2]+red[3])*(1.0f/512.0f) + 1e-5f);
  __syncthreads();
  float rstd = stat;
  out[(long)row*out_stride + threadIdx.x]     = d0*rstd*g[threadIdx.x]     + b[threadIdx.x];
  out[(long)row*out_stride + threadIdx.x+256] = d1*rstd*g[threadIdx.x+256] + b[threadIdx.x+256];
}

// ---------- Generic small GEMM: out = [res +] act(A@W + bias)
__global__ __launch_bounds__(256) void gemm_rows(
    const float* __restrict__ A, const float* __restrict__ W,
    const float* __restrict__ bias, const float* __restrict__ res,
    float* __restrict__ out, int M, int N, int K, int dogelu)
{
  __shared__ float A_s[16][33];
  __shared__ __align__(16) float W_s[32][68];
  const int m0 = blockIdx.x*16, n0 = blockIdx.y*64;
  const int r = threadIdx.x>>4, c0 = (threadIdx.x&15)*4;
  float acc[4] = {};
  for (int k0 = 0; k0 < K; k0 += 32){
    __syncthreads();
    for (int i = 0; i < 2; i++){ int id = threadIdx.x + i*256; int rr = id>>5, kk = id&31;
      A_s[rr][kk] = (m0+rr < M) ? A[(long)(m0+rr)*K + k0+kk] : 0.f; }
    for (int i = 0; i < 8; i++){ int id = threadIdx.x + i*256; int kk = id>>6, c = id&63;
      W_s[kk][c] = (n0+c < N) ? W[(long)(k0+kk)*N + n0+c] : 0.f; }
    __syncthreads();
    #pragma unroll
    for (int kk = 0; kk < 32; kk++){
      float a = A_s[r][kk];
      float4 w4 = *(const float4*)&W_s[kk][c0];
      acc[0]+=a*w4.x; acc[1]+=a*w4.y; acc[2]+=a*w4.z; acc[3]+=a*w4.w;
    }
  }
  if (m0+r < M){
    int row = m0+r;
    for (int j = 0; j < 4; j++){
      int c = n0+c0+j;
      if (c < N){
        float v = acc[j];
        if (bias) v += bias[c];
        if (dogelu) v = 0.5f*v*(1.0f + erff(v*0.70710678118654752f));
        if (res) v += res[(long)row*N + c];
        out[(long)row*N + c] = v;
      }
    }
  }
}

// ---------- Attention: one block per (b,h). N=17, DH=64.
__global__ __launch_bounds__(128) void attn_kernel(
    const float* __restrict__ qkv, float* __restrict__ obuf)
{
  const int b = blockIdx.x >> 3, h = blockIdx.x & 7;
  __shared__ float q_s[17][65], k_s[17][65], v_s[17][65], s_s[17][18];
  for (int idx = threadIdx.x; idx < 17*64; idx += 128){
    int i = idx>>6, d = idx&63;
    const float* base = qkv + (long)(b*17+i)*1536 + h*64 + d;
    q_s[i][d] = base[0]; k_s[i][d] = base[512]; v_s[i][d] = base[1024];
  }
  __syncthreads();
  for (int idx = threadIdx.x; idx < 289; idx += 128){
    int i = idx/17, j = idx - i*17;
    float s = 0.f;
    for (int d = 0; d < 64; d++) s += q_s[i][d]*k_s[j][d];
    s_s[i][j] = s*0.125f;
  }
  __syncthreads();
  if (threadIdx.x < 17){
    int i = threadIdx.x;
    float m = -1e30f;
    for (int j = 0; j < 17; j++) m = fmaxf(m, s_s[i][j]);
    float sum = 0.f;
    for (int j = 0; j < 17; j++){ float e = expf(s_s[i][j]-m); s_s[i][j] = e; sum += e; }
    float inv = 1.0f/sum;
    for (int j = 0; j < 17; j++) s_s[i][j] *= inv;
  }
  __syncthreads();
  for (int idx = threadIdx.x; idx < 17*64; idx += 128){
    int i = idx>>6, d = idx&63;
    float o = 0.f;
    for (int j = 0; j < 17; j++) o += s_s[i][j]*v_s[j][d];
    obuf[(long)(b*17+i)*512 + h*64 + d] = o;
  }
}

// ============================================================================
extern "C" void kernel_launch(void* const* d_in, const int* in_sizes, int n_in,
                              void* d_out, int out_size, void* d_ws, size_t ws_size,
                              hipStream_t stream) {
  const float* img      = (const float*)d_in[0];
  const float* conv1_w  = (const float*)d_in[1];
  const float* conv2_w  = (const float*)d_in[2];
  const float* conv3_w  = (const float*)d_in[3];
  const float* flat_w   = (const float*)d_in[4];
  const float* flat_b   = (const float*)d_in[5];
  const float* cls_tok  = (const float*)d_in[6];
  const float* pos_emb  = (const float*)d_in[7];
  const float* ln1_g    = (const float*)d_in[8];
  const float* ln1_b    = (const float*)d_in[9];
  const float* qkv_w    = (const float*)d_in[10];
  const float* out_w    = (const float*)d_in[11];
  const float* out_b    = (const float*)d_in[12];
  const float* ln2_g    = (const float*)d_in[13];
  const float* ln2_b    = (const float*)d_in[14];
  const float* ff1_w    = (const float*)d_in[15];
  const float* ff1_b    = (const float*)d_in[16];
  const float* ff2_w    = (const float*)d_in[17];
  const float* ff2_b    = (const float*)d_in[18];
  const float* hln_g    = (const float*)d_in[19];
  const float* hln_b    = (const float*)d_in[20];
  const float* head_w   = (const float*)d_in[21];
  const float* head_b   = (const float*)d_in[22];

  char* ws = (char*)d_ws;
  size_t off = 0;
  auto alloc = [&](size_t bytes) -> void* {
    void* p = ws + off; off += (bytes + 255) & ~(size_t)255; return p;
  };
  bf16* pool1    = (bf16*)alloc((size_t)CHUNK*8*103*103*4*2); // 43.5 MB (chunk, blocked)
  bf16* conv2out = (bf16*)alloc((size_t)CHUNK*49*49*64*2);    // 19.7 MB (chunk, NHWC)
  bf16* pool2    = (bf16*)alloc((size_t)256*45*45*64*2);      // 66.4 MB (full, NHWC)
  bf16* feat     = (bf16*)alloc((size_t)256*16384*2);         //  8.4 MB
  bf16* w2b      = (bf16*)alloc((size_t)49*64*32*2);
  bf16* w3b      = (bf16*)alloc((size_t)49*2*64*32*2);
  float* x       = (float*)alloc((size_t)139264*4);
  float* h       = (float*)alloc((size_t)139264*4);
  float* qkvb    = (float*)alloc((size_t)417792*4);
  float* obuf    = (float*)alloc((size_t)139264*4);
  float* ffbuf   = (float*)alloc((size_t)557056*4);
  float* hcls    = (float*)alloc((size_t)8192*4);
  bf16* tmp3     = pool1;   // k3 horizontal tmp: 18.1 MB <= 43.5 MB (pool1 dead)
  bf16* conv3out = pool1;   // k4 output: 13.1 MB <= 43.5 MB (pool1 dead)
  (void)ws_size; (void)in_sizes; (void)n_in; (void)out_size;

  prep_w2<<<392, 256, 0, stream>>>(conv2_w, w2b);
  prep_w3<<<784, 256, 0, stream>>>(conv3_w, w3b);

  for (int cb = 0; cb < 256; cb += CHUNK){
    k1_conv1_pool<<<dim3(8,CHUNK),  256, 0, stream>>>(img, conv1_w, pool1, cb);
    k2_conv2     <<<dim3(10,CHUNK), 256, 0, stream>>>(pool1, w2b, conv2out);
    k3a_hmax     <<<(CHUNK*49*45*8)/256, 256, 0, stream>>>(conv2out, tmp3);
    k3b_vmax     <<<(CHUNK*45*45*8)/256, 256, 0, stream>>>(tmp3, pool2, cb);
  }
  k4_conv3<<<dim3(2,256), 256, 0, stream>>>(pool2, w3b, conv3out);
  k5_pool3<<<256, 256, 0, stream>>>(conv3out, feat);

  k6_init_x    <<<544,          256, 0, stream>>>(cls_tok, pos_emb, flat_b, x);
  k6_flat_gemm <<<dim3(8,8,8),  256, 0, stream>>>(feat, flat_w, x);

  for (int l = 0; l < 6; l++){
    ln_kernel<<<272, 256, 0, stream>>>(x, ln1_g + l*512, ln1_b + l*512, h, 512, 512);
    gemm_rows<<<dim3(17,24), 256, 0, stream>>>(h, qkv_w + (size_t)l*786432,
                                               nullptr, nullptr, qkvb, 272, 1536, 512, 0);
    attn_kernel<<<128, 128, 0, stream>>>(qkvb, obuf);
    gemm_rows<<<dim3(17,8), 256, 0, stream>>>(obuf, out_w + (size_t)l*262144,
                                              out_b + l*512, x, x, 272, 512, 512, 0);
    ln_kernel<<<272, 256, 0, stream>>>(x, ln2_g + l*512, ln2_b + l*512, h, 512, 512);
    gemm_rows<<<dim3(17,32), 256, 0, stream>>>(h, ff1_w + (size_t)l*1048576,
                                               ff1_b + l*2048, nullptr, ffbuf, 272, 2048, 512, 1);
    gemm_rows<<<dim3(17,8), 256, 0, stream>>>(ffbuf, ff2_w + (size_t)l*1048576,
                                              ff2_b + l*512, x, x, 272, 512, 2048, 0);
  }

  ln_kernel<<<16, 256, 0, stream>>>(x, hln_g, hln_b, hcls, 17*512, 512);
  gemm_rows<<<dim3(1,16), 256, 0, stream>>>(hcls, head_w, head_b, nullptr,
                                            (float*)d_out, 16, 1000, 512, 0);
}

// Round 6
// 2230.542 us; speedup vs baseline: 4.4839x; 1.7556x over previous
//
#include <hip/hip_runtime.h>
#include <hip/hip_bf16.h>

// ============================================================================
// HybridViT forward. Round 6: transformer tail -> bf16 MFMA.
//  - tail_gemm: LDS-free MFMA GEMM; A = bf16 activations (L2-resident rows),
//    B = weights pre-packed [K/8][N][8] bf16 so each lane's fragment is one
//    contiguous short8. fp32 epilogue (bias/GELU/residual).
//  - LN kernels emit bf16; attention emits bf16 O. Head stays fp32.
//  - Packed weights alias dead pool1 region after k5 (no ws growth).
//  - k2/k4: #pragma unroll on kx loops (pipeline per-tap A-fragment loads).
// k1 frozen this round (round-7 target with clean attribution).
// ============================================================================

typedef __hip_bfloat16 bf16;
typedef __attribute__((ext_vector_type(8))) short short8;
typedef __attribute__((ext_vector_type(4))) float floatx4;

#define CHUNK 64

union U8 { int4 v; unsigned short s[8]; };
__device__ inline void umax8(U8& a, const U8& b){
  #pragma unroll
  for (int j = 0; j < 8; j++) a.s[j] = (a.s[j] > b.s[j]) ? a.s[j] : b.s[j];
}

// ---------- weight prep: conv2_w fp32 [64][32][7][7] -> bf16 [ky*7+kx][64][32]
__global__ __launch_bounds__(256) void prep_w2(const float* __restrict__ w,
                                               bf16* __restrict__ w2b)
{
  int idx = blockIdx.x*256 + threadIdx.x;     // 49*64*32 = 100352
  if (idx >= 49*64*32) return;
  int ic = idx & 31; int t = idx >> 5; int oc = t & 63; int kk = t >> 6;
  int ky = kk/7, kx = kk - ky*7;
  w2b[idx] = __float2bfloat16(w[((oc*32+ic)*7+ky)*7+kx]);
}

// ---------- weight prep: conv3_w fp32 [64][64][7][7] -> bf16 [ky][kc][kx][64][32]
__global__ __launch_bounds__(256) void prep_w3(const float* __restrict__ w,
                                               bf16* __restrict__ w3b)
{
  int idx = blockIdx.x*256 + threadIdx.x;     // 49*2*64*32 = 200704
  if (idx >= 49*2*64*32) return;
  int ic_l = idx & 31; int t = idx >> 5; int oc = t & 63; int t2 = t >> 6;
  int kx = t2 % 7; int t3 = t2 / 7; int kc = t3 & 1; int ky = t3 >> 1;
  w3b[idx] = __float2bfloat16(w[((oc*64 + kc*32 + ic_l)*7+ky)*7+kx]);
}

// ---------- transformer weight pack: fp32 [L][K][N] -> bf16 [L][K/8][N][8]
// One thread per (l,k8,n): 8 coalesced row reads, one int4 coalesced write.
__global__ __launch_bounds__(256) void prep_pack(
    const float* __restrict__ src, bf16* __restrict__ dst,
    int K8, int N, int total)
{
  int idx = blockIdx.x*256 + threadIdx.x;
  if (idx >= total) return;
  int n = idx % N; int t = idx / N; int k8 = t % K8; int l = t / K8;
  const float* s = src + ((size_t)l*K8*8 + (size_t)k8*8)*N + n;
  union { bf16 h[8]; int4 v; } pk;
  #pragma unroll
  for (int j = 0; j < 8; j++) pk.h[j] = __float2bfloat16(s[(size_t)j*N]);
  *(int4*)(dst + (((size_t)l*K8 + k8)*N + n)*8) = pk.v;
}

// ---------- K1: patchify + conv1(1->32,7x7,s2) + ReLU + separable pool
//   -> pool1 blocked [CHUNK][8grp][103][103][4ch] bf16
__global__ __launch_bounds__(256) void k1_conv1_pool(
    const float* __restrict__ img, const float* __restrict__ w,
    bf16* __restrict__ pool1, int n_base)
{
  __shared__ __align__(16) float in_s[43*224];
  __shared__ __align__(16) unsigned short conv_s[4*19*112];
  __shared__ __align__(16) float w_s[32*56];
  __shared__ __align__(16) unsigned short vtmp_s[13*112*4];
  const int strip = blockIdx.x;        // 0..7
  const int n = blockIdx.y;
  const int ng = n_base + n;
  const int p0 = strip*13;
  const int PR = min(13, 103-p0);
  const int cr0 = max(p0-1, 0);
  const int cr1 = min(p0+PR+4, 106);
  const int CR = cr1-cr0+1;
  const int ir0 = 2*cr0;
  const int IR = 2*CR+5;
  const int b = ng>>4, gh = (ng>>2)&3, gw = ng&3;
  const float* ibase = img + b*774400 + (gh*220)*880 + gw*220;

  for (int idx = threadIdx.x; idx < IR*56; idx += 256){
    int r = idx/56, cq = idx - r*56; int c = cq*4;
    float4 v = (c < 220) ? *(const float4*)(ibase + (ir0+r)*880 + c)
                         : make_float4(0.f,0.f,0.f,0.f);
    *(float4*)&in_s[r*224 + c] = v;
  }
  for (int idx = threadIdx.x; idx < 32*56; idx += 256){
    int oc = idx/56, k = idx - oc*56; int ky = k>>3, kx = k&7;
    w_s[idx] = (kx < 7 && ky < 7) ? w[oc*49 + ky*7 + kx] : 0.f;
  }
  __syncthreads();

  for (int grp = 0; grp < 8; grp++){
    for (int t = threadIdx.x; t < CR*27; t += 256){
      int r = t/27, g = t - r*27; int c0 = g*4;
      float acc[4][4] = {};
      for (int ky = 0; ky < 7; ky++){
        const float* ip = &in_s[(2*r+ky)*224 + 2*c0];
        float iv[13];
        *(float4*)&iv[0] = *(const float4*)ip;
        *(float4*)&iv[4] = *(const float4*)(ip+4);
        *(float4*)&iv[8] = *(const float4*)(ip+8);
        iv[12] = ip[12];
        #pragma unroll
        for (int oc = 0; oc < 4; oc++){
          const float* wp = &w_s[(grp*4+oc)*56 + ky*8];
          float4 wa = *(const float4*)wp;
          float4 wb = *(const float4*)(wp+4);
          float wk[7] = {wa.x,wa.y,wa.z,wa.w,wb.x,wb.y,wb.z};
          #pragma unroll
          for (int kx = 0; kx < 7; kx++)
            #pragma unroll
            for (int j = 0; j < 4; j++)
              acc[oc][j] += iv[2*j+kx]*wk[kx];
        }
      }
      #pragma unroll
      for (int oc = 0; oc < 4; oc++){
        union { unsigned short s[4]; uint2 u; } pk;
        #pragma unroll
        for (int j = 0; j < 4; j++){
          bf16 hv = __float2bfloat16(fmaxf(acc[oc][j], 0.f));
          pk.s[j] = *(unsigned short*)&hv;
        }
        *(uint2*)&conv_s[(oc*19 + r)*112 + c0] = pk.u;
      }
    }
    __syncthreads();
    for (int t = threadIdx.x; t < PR*107*4; t += 256){
      int oc = t & 3; int t2 = t >> 2; int c = t2 % 107; int pr = t2/107;
      int py = p0 + pr;
      unsigned short m = 0;
      for (int dy = 0; dy < 7; dy++){
        int rr = py-1+dy;
        if (rr < 0 || rr > 106) continue;
        unsigned short v = conv_s[(oc*19 + (rr - cr0))*112 + c];
        m = (v > m) ? v : m;
      }
      vtmp_s[(pr*112 + c)*4 + oc] = m;
    }
    __syncthreads();
    for (int t = threadIdx.x; t < PR*103; t += 256){
      int pc = t % 103; int pr = t/103;
      int py = p0 + pr;
      unsigned short m0=0, m1=0, m2=0, m3=0;
      int lo = max(pc-1, 0), hi = min(pc+5, 106);
      for (int cc = lo; cc <= hi; cc++){
        union { uint2 u; unsigned short s[4]; } v;
        v.u = *(const uint2*)&vtmp_s[(pr*112 + cc)*4];
        m0 = (v.s[0] > m0) ? v.s[0] : m0;
        m1 = (v.s[1] > m1) ? v.s[1] : m1;
        m2 = (v.s[2] > m2) ? v.s[2] : m2;
        m3 = (v.s[3] > m3) ? v.s[3] : m3;
      }
      union { unsigned short s[4]; uint2 u; } pk;
      pk.s[0]=m0; pk.s[1]=m1; pk.s[2]=m2; pk.s[3]=m3;
      *(uint2*)((unsigned short*)pool1 +
                ((size_t)(n*8 + grp)*10609 + py*103 + pc)*4) = pk.u;
    }
    __syncthreads();
  }
}

// ---------- K2: conv2 MFMA implicit GEMM. pool1 blocked -> conv2out NHWC [CHUNK,49,49,64]
__global__ __launch_bounds__(256) void k2_conv2(
    const bf16* __restrict__ pool1,   // [CHUNK][8][103][103][4]
    const bf16* __restrict__ w2b,     // [49][64][32]
    bf16* __restrict__ conv2out)      // [CHUNK][49][49][64]
{
  __shared__ __align__(16) bf16 in_s[7*2*52*40];   // 58240 B
  const int n = blockIdx.y, pb = blockIdx.x;       // pb 0..9
  const int wv = threadIdx.x >> 6, lane = threadIdx.x & 63;
  const int li = lane & 15, lg = lane >> 4;
  const int p0 = pb*256;
  const int y0 = p0/49;

  int pyv[4], pxv[4], poff[4]; bool pmask[4];
  #pragma unroll
  for (int t = 0; t < 4; t++){
    int p = p0 + wv*64 + t*16 + li;
    pmask[t] = (p <= 2400);
    int pc = min(p, 2400);
    int yy = pc/49, xx = pc - yy*49;
    pyv[t] = yy; pxv[t] = xx;
    poff[t] = ((yy - y0)*2*52 + xx)*40;
  }
  floatx4 acc[4][4];
  #pragma unroll
  for (int a = 0; a < 4; a++)
    #pragma unroll
    for (int t = 0; t < 4; t++) acc[a][t] = (floatx4){0.f,0.f,0.f,0.f};

  const unsigned short* pbase = (const unsigned short*)pool1;
  for (int ky = 0; ky < 7; ky++){
    __syncthreads();
    for (int idx = threadIdx.x; idx < 7*103*4; idx += 256){
      int q = idx & 3; int t2 = idx >> 2; int c = t2 % 103; int r = t2/103;
      int gr = min(2*(y0+r)+ky, 102);
      size_t pix = (size_t)gr*103 + c;
      uint2 lov = *(const uint2*)(pbase + (((size_t)n*8 + 2*q  )*10609 + pix)*4);
      uint2 hiv = *(const uint2*)(pbase + (((size_t)n*8 + 2*q+1)*10609 + pix)*4);
      int4 vv; vv.x = (int)lov.x; vv.y = (int)lov.y; vv.z = (int)hiv.x; vv.w = (int)hiv.y;
      *(int4*)&in_s[((r*2 + (c&1))*52 + (c>>1))*40 + q*8] = vv;
    }
    __syncthreads();
    #pragma unroll
    for (int kx = 0; kx < 7; kx++){
      short8 a[4];
      const bf16* wp = w2b + (ky*7+kx)*64*32;
      #pragma unroll
      for (int ot = 0; ot < 4; ot++)
        a[ot] = *(const short8*)(wp + (ot*16 + li)*32 + lg*8);
      int koff = ((kx&1)*52 + (kx>>1))*40 + lg*8;
      #pragma unroll
      for (int t = 0; t < 4; t++){
        short8 bfr = *(const short8*)(&in_s[poff[t] + koff]);
        #pragma unroll
        for (int ot = 0; ot < 4; ot++)
          acc[ot][t] = __builtin_amdgcn_mfma_f32_16x16x32_bf16(a[ot], bfr, acc[ot][t], 0, 0, 0);
      }
    }
  }
  #pragma unroll
  for (int t = 0; t < 4; t++){
    if (!pmask[t]) continue;
    bf16* dst = conv2out + (((long)n*49 + pyv[t])*49 + pxv[t])*64 + lg*4;
    #pragma unroll
    for (int ot = 0; ot < 4; ot++){
      union { bf16 h[4]; uint2 u; } pk;
      #pragma unroll
      for (int v = 0; v < 4; v++)
        pk.h[v] = __float2bfloat16(fmaxf(acc[ot][t][v], 0.f));
      *(uint2*)(dst + ot*16) = pk.u;
    }
  }
}

// ---------- K3a: horizontal 7-max: conv2out [CHUNK,49,49,64] -> tmp [CHUNK,49,45,64]
__global__ __launch_bounds__(256) void k3a_hmax(
    const bf16* __restrict__ cin, bf16* __restrict__ tmp)
{
  int idx = blockIdx.x*256 + threadIdx.x;
  int cg = idx & 7; int t = idx >> 3; int x = t % 45; int t2 = t / 45;
  int y = t2 % 49; int n = t2 / 49;
  const int4* row = (const int4*)(cin + ((long)(n*49 + y)*49)*64) + cg;
  U8 m; m.v = make_int4(0,0,0,0);
  int lo = max(x-1, 0), hi = min(x+5, 48);
  for (int cx = lo; cx <= hi; cx++){ U8 v; v.v = row[cx*8]; umax8(m, v); }
  *((int4*)(tmp + ((long)(n*49 + y)*45 + x)*64) + cg) = m.v;
}

// ---------- K3b: vertical 7-max: tmp -> pool2 [256,45,45,64] at n_base
__global__ __launch_bounds__(256) void k3b_vmax(
    const bf16* __restrict__ tmp, bf16* __restrict__ pout, int n_base)
{
  int idx = blockIdx.x*256 + threadIdx.x;
  int cg = idx & 7; int t = idx >> 3; int x = t % 45; int t2 = t / 45;
  int y = t2 % 45; int n = t2 / 45;
  U8 m; m.v = make_int4(0,0,0,0);
  int lo = max(y-1, 0), hi = min(y+5, 48);
  for (int cy = lo; cy <= hi; cy++){
    U8 v; v.v = *((const int4*)(tmp + ((long)(n*49 + cy)*45 + x)*64) + cg);
    umax8(m, v);
  }
  *((int4*)(pout + (long)(n_base+n)*129600 + (y*45 + x)*64) + cg) = m.v;
}

// ---------- K4: conv3 MFMA implicit GEMM. pool2 NHWC -> conv3out NHWC [256,20,20,64]
__global__ __launch_bounds__(256) void k4_conv3(
    const bf16* __restrict__ pool2,
    const bf16* __restrict__ w3b,     // [ky][kc][kx][64][32]
    bf16* __restrict__ conv3out)
{
  __shared__ __align__(16) bf16 in_s[10*2*24*40];  // 38400 B
  const int n = blockIdx.y, pb = blockIdx.x;       // pb 0..1
  const int wv = threadIdx.x >> 6, lane = threadIdx.x & 63;
  const int li = lane & 15, lg = lane >> 4;
  const int y0 = pb*10;

  int pyv[4], pxv[4], poff[4]; bool pmask[4];
  #pragma unroll
  for (int t = 0; t < 4; t++){
    int pl = wv*64 + t*16 + li;
    pmask[t] = (pl < 200);
    int p = pb*200 + min(pl, 199);
    int yy = p/20, xx = p - yy*20;
    pyv[t] = yy; pxv[t] = xx;
    poff[t] = ((yy - y0)*2*24 + xx)*40;
  }
  floatx4 acc[4][4];
  #pragma unroll
  for (int a = 0; a < 4; a++)
    #pragma unroll
    for (int t = 0; t < 4; t++) acc[a][t] = (floatx4){0.f,0.f,0.f,0.f};

  for (int ky = 0; ky < 7; ky++){
    for (int kc = 0; kc < 2; kc++){
      __syncthreads();
      for (int idx = threadIdx.x; idx < 10*45*4; idx += 256){
        int q = idx & 3; int t2 = idx >> 2; int c = t2 % 45; int r = t2/45;
        int gr = 2*(y0+r)+ky;
        const bf16* src = pool2 + (((long)n*45 + gr)*45 + c)*64 + kc*32 + q*8;
        bf16* dst = &in_s[((r*2 + (c&1))*24 + (c>>1))*40 + q*8];
        *(int4*)dst = *(const int4*)src;
      }
      __syncthreads();
      #pragma unroll
      for (int kx = 0; kx < 7; kx++){
        short8 a[4];
        const bf16* wp = w3b + ((ky*2+kc)*7 + kx)*64*32;
        #pragma unroll
        for (int ot = 0; ot < 4; ot++)
          a[ot] = *(const short8*)(wp + (ot*16 + li)*32 + lg*8);
        int koff = ((kx&1)*24 + (kx>>1))*40 + lg*8;
        #pragma unroll
        for (int t = 0; t < 4; t++){
          short8 bfr = *(const short8*)(&in_s[poff[t] + koff]);
          #pragma unroll
          for (int ot = 0; ot < 4; ot++)
            acc[ot][t] = __builtin_amdgcn_mfma_f32_16x16x32_bf16(a[ot], bfr, acc[ot][t], 0, 0, 0);
        }
      }
    }
  }
  #pragma unroll
  for (int t = 0; t < 4; t++){
    if (!pmask[t]) continue;
    bf16* dst = conv3out + (((long)n*20 + pyv[t])*20 + pxv[t])*64 + lg*4;
    #pragma unroll
    for (int ot = 0; ot < 4; ot++){
      union { bf16 h[4]; uint2 u; } pk;
      #pragma unroll
      for (int v = 0; v < 4; v++)
        pk.h[v] = __float2bfloat16(fmaxf(acc[ot][t][v], 0.f));
      *(uint2*)(dst + ot*16) = pk.u;
    }
  }
}

// ---------- K5: in-LDS separable pool3. conv3out [256,20,20,64] -> feat [256,16384]
__global__ __launch_bounds__(256) void k5_pool3(
    const bf16* __restrict__ cin, bf16* __restrict__ feat)
{
  __shared__ int4 in_p[3200];
  __shared__ int4 ht[2560];
  const int n = blockIdx.x;
  const int4* src = (const int4*)(cin + (long)n*25600);
  for (int i = threadIdx.x; i < 3200; i += 256) in_p[i] = src[i];
  __syncthreads();
  for (int i = threadIdx.x; i < 2560; i += 256){
    int cg = i & 7; int t = i >> 3; int x = t & 15; int y = t >> 4;
    U8 m; m.v = make_int4(0,0,0,0);
    int lo = max(x-1, 0), hi = min(x+5, 19);
    for (int cx = lo; cx <= hi; cx++){ U8 v; v.v = in_p[(y*20+cx)*8 + cg]; umax8(m, v); }
    ht[(y*16+x)*8 + cg] = m.v;
  }
  __syncthreads();
  unsigned short* dst = (unsigned short*)(feat + (long)n*16384);
  for (int i = threadIdx.x; i < 2048; i += 256){
    int px = i & 15; int py = (i >> 4) & 15; int cg = i >> 8;
    U8 m; m.v = make_int4(0,0,0,0);
    int lo = max(py-1, 0), hi = min(py+5, 19);
    for (int cy = lo; cy <= hi; cy++){ U8 v; v.v = ht[(cy*16+px)*8 + cg]; umax8(m, v); }
    #pragma unroll
    for (int j = 0; j < 8; j++)
      dst[(cg*8+j)*256 + py*16 + px] = m.s[j];
  }
}

// ---------- K6a: init x[272,512]
__global__ __launch_bounds__(256) void k6_init_x(
    const float* __restrict__ cls, const float* __restrict__ pos,
    const float* __restrict__ flat_b, float* __restrict__ x)
{
  int idx = blockIdx.x*256 + threadIdx.x;
  int d = idx & 511; int row = idx >> 9;
  int tt = row % 17;
  x[idx] = (tt == 0) ? (cls[d] + pos[d]) : (flat_b[d] + pos[tt*512 + d]);
}

// ---------- K6b: feat @ flat_w -> atomicAdd into x
__global__ __launch_bounds__(256) void k6_flat_gemm(
    const bf16* __restrict__ feat, const float* __restrict__ W,
    float* __restrict__ x)
{
  __shared__ float A_s[32][33];
  __shared__ __align__(16) float W_s[32][68];
  const int m0 = blockIdx.x*32, n0 = blockIdx.y*64, ks = blockIdx.z;
  const int r = threadIdx.x>>4, c0 = (threadIdx.x&15)*4;
  float acc0[4] = {}, acc1[4] = {};
  for (int kt = 0; kt < 64; kt++){
    int k0 = ks*2048 + kt*32;
    __syncthreads();
    for (int i = 0; i < 4; i++){ int id = threadIdx.x + i*256; int rr = id>>5, kk = id&31;
      A_s[rr][kk] = __bfloat162float(feat[(long)(m0+rr)*16384 + k0+kk]); }
    for (int i = 0; i < 8; i++){ int id = threadIdx.x + i*256; int kk = id>>6, c = id&63;
      W_s[kk][c] = W[(long)(k0+kk)*512 + n0+c]; }
    __syncthreads();
    #pragma unroll
    for (int kk = 0; kk < 32; kk++){
      float a0 = A_s[r][kk], a1 = A_s[r+16][kk];
      float4 w4 = *(const float4*)&W_s[kk][c0];
      acc0[0]+=a0*w4.x; acc0[1]+=a0*w4.y; acc0[2]+=a0*w4.z; acc0[3]+=a0*w4.w;
      acc1[0]+=a1*w4.x; acc1[1]+=a1*w4.y; acc1[2]+=a1*w4.z; acc1[3]+=a1*w4.w;
    }
  }
  int ma = m0+r, mb = m0+r+16;
  int rowa = (ma>>4)*17 + 1 + (ma&15);
  int rowb = (mb>>4)*17 + 1 + (mb&15);
  for (int j = 0; j < 4; j++){
    atomicAdd(&x[rowa*512 + n0+c0+j], acc0[j]);
    atomicAdd(&x[rowb*512 + n0+c0+j], acc1[j]);
  }
}

// ---------- LayerNorm over 512, fp32 out (head path)
__global__ __launch_bounds__(256) void ln_kernel(
    const float* __restrict__ in, const float* __restrict__ g,
    const float* __restrict__ b, float* __restrict__ out,
    int in_stride, int out_stride)
{
  int row = blockIdx.x;
  const float* p = in + (long)row*in_stride;
  float v0 = p[threadIdx.x], v1 = p[threadIdx.x+256];
  __shared__ float red[4]; __shared__ float stat;
  float s = v0+v1;
  #pragma unroll
  for (int o = 32; o >= 1; o >>= 1) s += __shfl_down(s, o);
  int lane = threadIdx.x & 63, wv = threadIdx.x >> 6;
  if (lane == 0) red[wv] = s;
  __syncthreads();
  if (threadIdx.x == 0) stat = (red[0]+red[1]+red[2]+red[3])*(1.0f/512.0f);
  __syncthreads();
  float m = stat;
  float d0 = v0-m, d1 = v1-m;
  float q = d0*d0 + d1*d1;
  #pragma unroll
  for (int o = 32; o >= 1; o >>= 1) q += __shfl_down(q, o);
  __syncthreads();
  if (lane == 0) red[wv] = q;
  __syncthreads();
  if (threadIdx.x == 0) stat = rsqrtf((red[0]+red[1]+red[2]+red[3])*(1.0f/512.0f) + 1e-5f);
  __syncthreads();
  float rstd = stat;
  out[(long)row*out_stride + threadIdx.x]     = d0*rstd*g[threadIdx.x]     + b[threadIdx.x];
  out[(long)row*out_stride + threadIdx.x+256] = d1*rstd*g[threadIdx.x+256] + b[threadIdx.x+256];
}

// ---------- LayerNorm over 512, bf16 out (MFMA tail activations)
__global__ __launch_bounds__(256) void ln_bf16(
    const float* __restrict__ in, const float* __restrict__ g,
    const float* __restrict__ b, bf16* __restrict__ out)
{
  int row = blockIdx.x;
  const float* p = in + (long)row*512;
  float v0 = p[threadIdx.x], v1 = p[threadIdx.x+256];
  __shared__ float red[4]; __shared__ float stat;
  float s = v0+v1;
  #pragma unroll
  for (int o = 32; o >= 1; o >>= 1) s += __shfl_down(s, o);
  int lane = threadIdx.x & 63, wv = threadIdx.x >> 6;
  if (lane == 0) red[wv] = s;
  __syncthreads();
  if (threadIdx.x == 0) stat = (red[0]+red[1]+red[2]+red[3])*(1.0f/512.0f);
  __syncthreads();
  float m = stat;
  float d0 = v0-m, d1 = v1-m;
  float q = d0*d0 + d1*d1;
  #pragma unroll
  for (int o = 32; o >= 1; o >>= 1) q += __shfl_down(q, o);
  __syncthreads();
  if (lane == 0) red[wv] = q;
  __syncthreads();
  if (threadIdx.x == 0) stat = rsqrtf((red[0]+red[1]+red[2]+red[3])*(1.0f/512.0f) + 1e-5f);
  __syncthreads();
  float rstd = stat;
  out[(long)row*512 + threadIdx.x]     = __float2bfloat16(d0*rstd*g[threadIdx.x]     + b[threadIdx.x]);
  out[(long)row*512 + threadIdx.x+256] = __float2bfloat16(d1*rstd*g[threadIdx.x+256] + b[threadIdx.x+256]);
}

// ---------- MFMA tail GEMM: out = [res +] act(A@W + bias)
// A bf16 [272][K] row-major; Wp bf16 packed [K/8][N][8]; no LDS, no barriers.
// Block: 16 rows x 64*NT cols (4 waves x NT 16x16 tiles).
template<int NT>
__global__ __launch_bounds__(256) void tail_gemm(
    const bf16* __restrict__ A, const bf16* __restrict__ Wp,
    const float* __restrict__ bias, const float* res,
    float* outf, bf16* outb, int N, int K, int dogelu)
{
  const int wv = threadIdx.x >> 6, lane = threadIdx.x & 63;
  const int li = lane & 15, lg = lane >> 4;
  const int m0 = blockIdx.x * 16;
  const int nb = blockIdx.y * (64*NT) + wv * (16*NT);
  floatx4 acc[NT];
  #pragma unroll
  for (int t = 0; t < NT; t++) acc[t] = (floatx4){0.f,0.f,0.f,0.f};
  const bf16* arow = A + (size_t)(m0+li)*K + lg*8;
  for (int k0 = 0; k0 < K; k0 += 32){
    short8 a = *(const short8*)(arow + k0);
    const bf16* wrow = Wp + ((size_t)((k0>>3) + lg) * N + nb + li) * 8;
    #pragma unroll
    for (int t = 0; t < NT; t++){
      short8 bfr = *(const short8*)(wrow + t*128);
      acc[t] = __builtin_amdgcn_mfma_f32_16x16x32_bf16(a, bfr, acc[t], 0, 0, 0);
    }
  }
  #pragma unroll
  for (int t = 0; t < NT; t++){
    int col = nb + t*16 + li;
    #pragma unroll
    for (int v = 0; v < 4; v++){
      int row = m0 + lg*4 + v;
      float val = acc[t][v];
      if (bias) val += bias[col];
      if (dogelu) val = 0.5f*val*(1.0f + erff(val*0.70710678118654752f));
      if (res) val += res[(size_t)row*N + col];
      if (outf) outf[(size_t)row*N + col] = val;
      else      outb[(size_t)row*N + col] = __float2bfloat16(val);
    }
  }
}

// ---------- Generic small GEMM (head only): out = act(A@W + bias)
__global__ __launch_bounds__(256) void gemm_rows(
    const float* __restrict__ A, const float* __restrict__ W,
    const float* __restrict__ bias, const float* __restrict__ res,
    float* __restrict__ out, int M, int N, int K, int dogelu)
{
  __shared__ float A_s[16][33];
  __shared__ __align__(16) float W_s[32][68];
  const int m0 = blockIdx.x*16, n0 = blockIdx.y*64;
  const int r = threadIdx.x>>4, c0 = (threadIdx.x&15)*4;
  float acc[4] = {};
  for (int k0 = 0; k0 < K; k0 += 32){
    __syncthreads();
    for (int i = 0; i < 2; i++){ int id = threadIdx.x + i*256; int rr = id>>5, kk = id&31;
      A_s[rr][kk] = (m0+rr < M) ? A[(long)(m0+rr)*K + k0+kk] : 0.f; }
    for (int i = 0; i < 8; i++){ int id = threadIdx.x + i*256; int kk = id>>6, c = id&63;
      W_s[kk][c] = (n0+c < N) ? W[(long)(k0+kk)*N + n0+c] : 0.f; }
    __syncthreads();
    #pragma unroll
    for (int kk = 0; kk < 32; kk++){
      float a = A_s[r][kk];
      float4 w4 = *(const float4*)&W_s[kk][c0];
      acc[0]+=a*w4.x; acc[1]+=a*w4.y; acc[2]+=a*w4.z; acc[3]+=a*w4.w;
    }
  }
  if (m0+r < M){
    int row = m0+r;
    for (int j = 0; j < 4; j++){
      int c = n0+c0+j;
      if (c < N){
        float v = acc[j];
        if (bias) v += bias[c];
        if (dogelu) v = 0.5f*v*(1.0f + erff(v*0.70710678118654752f));
        if (res) v += res[(long)row*N + c];
        out[(long)row*N + c] = v;
      }
    }
  }
}

// ---------- Attention: one block per (b,h). N=17, DH=64. Writes bf16 O.
__global__ __launch_bounds__(128) void attn_kernel(
    const float* __restrict__ qkv, bf16* __restrict__ obuf)
{
  const int b = blockIdx.x >> 3, h = blockIdx.x & 7;
  __shared__ float q_s[17][65], k_s[17][65], v_s[17][65], s_s[17][18];
  for (int idx = threadIdx.x; idx < 17*64; idx += 128){
    int i = idx>>6, d = idx&63;
    const float* base = qkv + (long)(b*17+i)*1536 + h*64 + d;
    q_s[i][d] = base[0]; k_s[i][d] = base[512]; v_s[i][d] = base[1024];
  }
  __syncthreads();
  for (int idx = threadIdx.x; idx < 289; idx += 128){
    int i = idx/17, j = idx - i*17;
    float s = 0.f;
    for (int d = 0; d < 64; d++) s += q_s[i][d]*k_s[j][d];
    s_s[i][j] = s*0.125f;
  }
  __syncthreads();
  if (threadIdx.x < 17){
    int i = threadIdx.x;
    float m = -1e30f;
    for (int j = 0; j < 17; j++) m = fmaxf(m, s_s[i][j]);
    float sum = 0.f;
    for (int j = 0; j < 17; j++){ float e = expf(s_s[i][j]-m); s_s[i][j] = e; sum += e; }
    float inv = 1.0f/sum;
    for (int j = 0; j < 17; j++) s_s[i][j] *= inv;
  }
  __syncthreads();
  for (int idx = threadIdx.x; idx < 17*64; idx += 128){
    int i = idx>>6, d = idx&63;
    float o = 0.f;
    for (int j = 0; j < 17; j++) o += s_s[i][j]*v_s[j][d];
    obuf[(long)(b*17+i)*512 + h*64 + d] = __float2bfloat16(o);
  }
}

// ============================================================================
extern "C" void kernel_launch(void* const* d_in, const int* in_sizes, int n_in,
                              void* d_out, int out_size, void* d_ws, size_t ws_size,
                              hipStream_t stream) {
  const float* img      = (const float*)d_in[0];
  const float* conv1_w  = (const float*)d_in[1];
  const float* conv2_w  = (const float*)d_in[2];
  const float* conv3_w  = (const float*)d_in[3];
  const float* flat_w   = (const float*)d_in[4];
  const float* flat_b   = (const float*)d_in[5];
  const float* cls_tok  = (const float*)d_in[6];
  const float* pos_emb  = (const float*)d_in[7];
  const float* ln1_g    = (const float*)d_in[8];
  const float* ln1_b    = (const float*)d_in[9];
  const float* qkv_w    = (const float*)d_in[10];
  const float* out_w    = (const float*)d_in[11];
  const float* out_b    = (const float*)d_in[12];
  const float* ln2_g    = (const float*)d_in[13];
  const float* ln2_b    = (const float*)d_in[14];
  const float* ff1_w    = (const float*)d_in[15];
  const float* ff1_b    = (const float*)d_in[16];
  const float* ff2_w    = (const float*)d_in[17];
  const float* ff2_b    = (const float*)d_in[18];
  const float* hln_g    = (const float*)d_in[19];
  const float* hln_b    = (const float*)d_in[20];
  const float* head_w   = (const float*)d_in[21];
  const float* head_b   = (const float*)d_in[22];

  char* ws = (char*)d_ws;
  size_t off = 0;
  auto alloc = [&](size_t bytes) -> void* {
    void* p = ws + off; off += (bytes + 255) & ~(size_t)255; return p;
  };
  bf16* pool1    = (bf16*)alloc((size_t)CHUNK*8*103*103*4*2); // 43.5 MB (chunk, blocked)
  bf16* conv2out = (bf16*)alloc((size_t)CHUNK*49*49*64*2);    // 19.7 MB (chunk, NHWC)
  bf16* pool2    = (bf16*)alloc((size_t)256*45*45*64*2);      // 66.4 MB (full, NHWC)
  bf16* feat     = (bf16*)alloc((size_t)256*16384*2);         //  8.4 MB
  bf16* w2b      = (bf16*)alloc((size_t)49*64*32*2);
  bf16* w3b      = (bf16*)alloc((size_t)49*2*64*32*2);
  float* x       = (float*)alloc((size_t)139264*4);           // 272x512 fp32
  bf16*  hb      = (bf16*)alloc((size_t)139264*2);            // 272x512 bf16 (LN out)
  float* qkvb    = (float*)alloc((size_t)417792*4);           // 272x1536 fp32
  bf16*  obufb   = (bf16*)alloc((size_t)139264*2);            // 272x512 bf16
  bf16*  ffbufb  = (bf16*)alloc((size_t)557056*2);            // 272x2048 bf16
  float* hcls    = (float*)alloc((size_t)8192*4);             // 16x512
  // pool1 region reuse (dead at the noted points):
  bf16* tmp3     = pool1;            // k3 horizontal tmp (within chunk loop)
  bf16* conv3out = pool1;            // k4 output (after chunk loop)
  // packed transformer weights alias pool1 AFTER k5 (pool1 fully dead):
  bf16* qkvp  = pool1;               //  9.44 MB
  bf16* outwp = qkvp  + (size_t)6*512*1536;   // 3.15 MB
  bf16* ff1p  = outwp + (size_t)6*512*512;    // 12.58 MB
  bf16* ff2p  = ff1p  + (size_t)6*512*2048;   // 12.58 MB  (total 37.75 <= 43.5)
  (void)ws_size; (void)in_sizes; (void)n_in; (void)out_size;

  prep_w2<<<392, 256, 0, stream>>>(conv2_w, w2b);
  prep_w3<<<784, 256, 0, stream>>>(conv3_w, w3b);

  for (int cb = 0; cb < 256; cb += CHUNK){
    k1_conv1_pool<<<dim3(8,CHUNK),  256, 0, stream>>>(img, conv1_w, pool1, cb);
    k2_conv2     <<<dim3(10,CHUNK), 256, 0, stream>>>(pool1, w2b, conv2out);
    k3a_hmax     <<<(CHUNK*49*45*8)/256, 256, 0, stream>>>(conv2out, tmp3);
    k3b_vmax     <<<(CHUNK*45*45*8)/256, 256, 0, stream>>>(tmp3, pool2, cb);
  }
  k4_conv3<<<dim3(2,256), 256, 0, stream>>>(pool2, w3b, conv3out);
  k5_pool3<<<256, 256, 0, stream>>>(conv3out, feat);

  // pack transformer weights into dead pool1 region (runs once per call)
  prep_pack<<<(6*64*1536+255)/256, 256, 0, stream>>>(qkv_w, qkvp, 64, 1536, 6*64*1536);
  prep_pack<<<(6*64*512 +255)/256, 256, 0, stream>>>(out_w, outwp, 64, 512,  6*64*512);
  prep_pack<<<(6*64*2048+255)/256, 256, 0, stream>>>(ff1_w, ff1p, 64, 2048, 6*64*2048);
  prep_pack<<<(6*256*512+255)/256, 256, 0, stream>>>(ff2_w, ff2p, 256, 512, 6*256*512);

  k6_init_x    <<<544,          256, 0, stream>>>(cls_tok, pos_emb, flat_b, x);
  k6_flat_gemm <<<dim3(8,8,8),  256, 0, stream>>>(feat, flat_w, x);

  for (int l = 0; l < 6; l++){
    ln_bf16<<<272, 256, 0, stream>>>(x, ln1_g + l*512, ln1_b + l*512, hb);
    tail_gemm<4><<<dim3(17,6), 256, 0, stream>>>(hb, qkvp + (size_t)l*786432,
                                                 nullptr, nullptr, qkvb, nullptr, 1536, 512, 0);
    attn_kernel<<<128, 128, 0, stream>>>(qkvb, obufb);
    tail_gemm<1><<<dim3(17,8), 256, 0, stream>>>(obufb, outwp + (size_t)l*262144,
                                                 out_b + l*512, x, x, nullptr, 512, 512, 0);
    ln_bf16<<<272, 256, 0, stream>>>(x, ln2_g + l*512, ln2_b + l*512, hb);
    tail_gemm<4><<<dim3(17,8), 256, 0, stream>>>(hb, ff1p + (size_t)l*1048576,
                                                 ff1_b + l*2048, nullptr, nullptr, ffbufb, 2048, 512, 1);
    tail_gemm<1><<<dim3(17,8), 256, 0, stream>>>(ffbufb, ff2p + (size_t)l*1048576,
                                                 ff2_b + l*512, x, x, nullptr, 512, 2048, 0);
  }

  ln_kernel<<<16, 256, 0, stream>>>(x, hln_g, hln_b, hcls, 17*512, 512);
  gemm_rows<<<dim3(1,16), 256, 0, stream>>>(hcls, head_w, head_b, nullptr,
                                            (float*)d_out, 16, 1000, 512, 0);
}